// Round 7
// baseline (325.244 us; speedup 1.0000x reference)
//
#include <hip/hip_runtime.h>

static constexpr int kDim   = 256;
static constexpr int kInner = 64;
static constexpr int kNH    = 8;
static constexpr int kHD    = 8;
static constexpr int kB     = 2;
static constexpr int kP     = 2304;   // 48*48
static constexpr float kScale = 0.35355339059327373f; // 8^-0.5
static constexpr float kEps   = 1e-6f;

typedef _Float16 half4f __attribute__((ext_vector_type(4)));
typedef float    f32x4  __attribute__((ext_vector_type(4)));

// ---------------- LayerNorm over channels (C=256), both images in one launch.
__global__ __launch_bounds__(256) void ln2_kernel(
    const float* __restrict__ x0, const float* __restrict__ w0,
    const float* __restrict__ b0, float* __restrict__ o0,
    const float* __restrict__ x1, const float* __restrict__ w1,
    const float* __restrict__ b1, float* __restrict__ o1)
{
    __shared__ float sb[16][16];
    __shared__ float ssb[16][16];
    const float* x = blockIdx.y ? x1 : x0;
    const float* w = blockIdx.y ? w1 : w0;
    const float* b = blockIdx.y ? b1 : b0;
    float*       o = blockIdx.y ? o1 : o0;
    const int pos = threadIdx.x & 15;
    const int grp = threadIdx.x >> 4;
    const int idx = blockIdx.x * 16 + pos;
    const int bb  = idx / kP;
    const int p   = idx - bb * kP;
    const size_t base = (size_t)bb * kDim * kP + p;
    const int c0 = grp * 16;

    float v[16];
    float s = 0.f, ss = 0.f;
    #pragma unroll
    for (int j = 0; j < 16; ++j) {
        v[j] = x[base + (size_t)(c0 + j) * kP];
        s += v[j]; ss += v[j] * v[j];
    }
    sb[grp][pos] = s; ssb[grp][pos] = ss;
    __syncthreads();
    float st = 0.f, sst = 0.f;
    #pragma unroll
    for (int g = 0; g < 16; ++g) { st += sb[g][pos]; sst += ssb[g][pos]; }
    const float mean = st * (1.f / kDim);
    const float rstd = rsqrtf(sst * (1.f / kDim) - mean * mean + kEps);
    #pragma unroll
    for (int j = 0; j < 16; ++j)
        o[base + (size_t)(c0 + j) * kP] = (v[j] - mean) * rstd * w[c0 + j] + b[c0 + j];
}

// ---------------- fused q/kv projections (C=256) -> f16 outputs for MFMA attn.
// XCD-affine 1-D grid (864): id&7 -> (inp,bb,half) panel combo, id>>3 -> (tile-pair, pos-chunk).
// Block: 128 positions x 2 tile-groups (og). 8 outputs/thread.
__global__ __launch_bounds__(256) void qkv_conv(
    const float* __restrict__ n_rgb, const float* __restrict__ n_ir,
    const float* __restrict__ qr_w, const float* __restrict__ qr_b,
    const float* __restrict__ kvr_w, const float* __restrict__ kvr_b,
    const float* __restrict__ qi_w, const float* __restrict__ qi_b,
    const float* __restrict__ kvi_w, const float* __restrict__ kvi_b,
    _Float16* __restrict__ q_r, _Float16* __restrict__ k_r, _Float16* __restrict__ vt_r,
    _Float16* __restrict__ q_i, _Float16* __restrict__ k_i, _Float16* __restrict__ vt_i)
{
    const int f    = blockIdx.x;             // 0..863
    const int xcd  = f & 7, q = f >> 3;      // q 0..107
    const int inp  = (xcd >> 2) & 1, bb = (xcd >> 1) & 1, half = xcd & 1;
    const int tp   = q % 12, pc = q / 12;    // 12 tile-pairs, 9 pos-chunks
    const int og   = threadIdx.x >> 7;
    const int tile = tp * 2 + og;            // 0..23
    const int p    = half * 1152 + pc * 128 + (threadIdx.x & 127);

    const float* in = inp ? n_ir : n_rgb;
    const float* w; const float* bias;
    if (tile < 8) { w = inp ? qi_w : qr_w;   bias = inp ? qi_b : qr_b;
                    w += (size_t)tile * 8 * kDim; bias += tile * 8; }
    else          { const int t = tile - 8;
                    w = inp ? kvi_w : kvr_w; bias = inp ? kvi_b : kvr_b;
                    w += (size_t)t * 8 * kDim; bias += t * 8; }
    const float* ip = in + (size_t)bb * kDim * kP + p;
    float acc[8];
    #pragma unroll
    for (int r = 0; r < 8; ++r) acc[r] = bias[r];
    #pragma unroll 4
    for (int c = 0; c < kDim; c += 4) {
        float v[4];
        #pragma unroll
        for (int j = 0; j < 4; ++j) v[j] = ip[(size_t)(c + j) * kP];
        #pragma unroll
        for (int r = 0; r < 8; ++r) {
            const float4 w4 = *(const float4*)(w + (size_t)r * kDim + c);
            const float* ww = (const float*)&w4;
            #pragma unroll
            for (int j = 0; j < 4; ++j) acc[r] = fmaf(ww[j], v[j], acc[r]);
        }
    }
    if (tile < 8) {                       // Q (scaled), pos-major
        _Float16* qp = (inp ? q_i : q_r) + ((size_t)(bb * kNH + tile) * kP + p) * 8;
        half4f lo = { (_Float16)(acc[0]*kScale), (_Float16)(acc[1]*kScale),
                      (_Float16)(acc[2]*kScale), (_Float16)(acc[3]*kScale) };
        half4f hi = { (_Float16)(acc[4]*kScale), (_Float16)(acc[5]*kScale),
                      (_Float16)(acc[6]*kScale), (_Float16)(acc[7]*kScale) };
        *(half4f*)qp = lo; *(half4f*)(qp + 4) = hi;
    } else if (tile < 16) {               // K, pos-major
        const int h = tile - 8;
        _Float16* kp = (inp ? k_i : k_r) + ((size_t)(bb * kNH + h) * kP + p) * 8;
        half4f lo = { (_Float16)acc[0], (_Float16)acc[1], (_Float16)acc[2], (_Float16)acc[3] };
        half4f hi = { (_Float16)acc[4], (_Float16)acc[5], (_Float16)acc[6], (_Float16)acc[7] };
        *(half4f*)kp = lo; *(half4f*)(kp + 4) = hi;
    } else {                              // V, transposed [bh][8][P]
        const int h = tile - 16;
        _Float16* vp = (inp ? vt_i : vt_r) + (size_t)(bb * kNH + h) * 8 * kP + p;
        #pragma unroll
        for (int d = 0; d < 8; ++d) vp[(size_t)d * kP] = (_Float16)acc[d];
    }
}

// ---------------- fused MFMA flash attention (both streams).
// grid (36, 16, 2): x = q-tile of 64, y = bh, z = stream. block 256 = 4 waves x 16 q.
__global__ __launch_bounds__(256) void attn_mfma(
    const _Float16* __restrict__ q0, const _Float16* __restrict__ k0, const _Float16* __restrict__ vt0,
    const _Float16* __restrict__ q1, const _Float16* __restrict__ k1, const _Float16* __restrict__ vt1,
    float* __restrict__ a0, float* __restrict__ a1)
{
    __shared__ _Float16 Ksm[256 * 24];   // 48B rows: halfs 0..7 = K[d], 8..15 = zeros
    __shared__ _Float16 Vsm[16 * 264];   // rows d (8 real + 8 zero), 264-half pitch
    const _Float16* Qg = blockIdx.z ? q1  : q0;
    const _Float16* Kg = blockIdx.z ? k1  : k0;
    const _Float16* Vg = blockIdx.z ? vt1 : vt0;
    float*          Ag = blockIdx.z ? a1  : a0;
    const int bh = blockIdx.y;
    const int bb = bh >> 3, h = bh & 7;
    const int tid  = threadIdx.x;
    const int wv   = tid >> 6;
    const int lane = tid & 63;
    const int r16  = lane & 15;
    const int g    = lane >> 4;

    {
        const float4 z4 = make_float4(0.f, 0.f, 0.f, 0.f);
        *(float4*)(Ksm + tid * 24 + 8) = z4;
        for (int i = tid; i < 264; i += 256)
            *(float4*)(Vsm + 8 * 264 + i * 8) = z4;
    }

    const int qg = blockIdx.x * 64 + wv * 16 + r16;
    half4f qf = (half4f){0, 0, 0, 0};
    if (g < 2) qf = *(const half4f*)(Qg + ((size_t)bh * kP + qg) * 8 + g * 4);

    f32x4 of = (f32x4){0.f, 0.f, 0.f, 0.f};
    float rs = 0.f;

    for (int ch = 0; ch < 9; ++ch) {
        if (ch) __syncthreads();
        const int p0 = ch * 256;
        *(float4*)(Ksm + tid * 24) = *(const float4*)(Kg + ((size_t)bh * kP + p0 + tid) * 8);
        {
            const int d = tid >> 5, c8 = (tid & 31) * 8;
            *(float4*)(Vsm + d * 264 + c8) =
                *(const float4*)(Vg + ((size_t)(bh * 8 + d)) * kP + p0 + c8);
        }
        __syncthreads();
        #pragma unroll
        for (int kt = 0; kt < 16; ++kt) {
            const half4f kf = *(const half4f*)(Ksm + (kt * 16 + r16) * 24 + g * 4);
            f32x4 s = __builtin_amdgcn_mfma_f32_16x16x16f16(kf, qf, (f32x4){0.f,0.f,0.f,0.f}, 0, 0, 0);
            const float e0 = __expf(s[0]), e1 = __expf(s[1]);
            const float e2 = __expf(s[2]), e3 = __expf(s[3]);
            rs += (e0 + e1) + (e2 + e3);
            const half4f pf = { (_Float16)e0, (_Float16)e1, (_Float16)e2, (_Float16)e3 };
            const half4f vf = *(const half4f*)(Vsm + r16 * 264 + kt * 16 + g * 4);
            of = __builtin_amdgcn_mfma_f32_16x16x16f16(vf, pf, of, 0, 0, 0);
        }
    }
    rs += __shfl_xor(rs, 16, 64);
    rs += __shfl_xor(rs, 32, 64);
    const float inv = 1.f / rs;
    if (g < 2) {
        float* op = Ag + ((size_t)(bb * kInner + h * 8 + g * 4)) * kP + qg;
        #pragma unroll
        for (int i = 0; i < 4; ++i) op[(size_t)i * kP] = of[i] * inv;
    }
}

// ---------------- output projection (C=64 -> O=256), both streams.
// XCD-affine 1-D grid (1152): id&7 -> (stream,bb,half), id>>3 -> (tile-pair, pos-chunk).
__global__ __launch_bounds__(256) void proj_conv(
    const float* __restrict__ a_rgb, const float* __restrict__ a_ir,
    const float* __restrict__ pr_w, const float* __restrict__ pr_b,
    const float* __restrict__ pi_w, const float* __restrict__ pi_b,
    float* __restrict__ c_rgb, float* __restrict__ c_ir)
{
    const int f   = blockIdx.x;              // 0..1151
    const int xcd = f & 7, q = f >> 3;       // q 0..143
    const int stream = (xcd >> 2) & 1, bb = (xcd >> 1) & 1, half = xcd & 1;
    const int tp = q & 15, pc = q >> 4;      // 16 tile-pairs, 9 pos-chunks
    const int ot = (tp * 2 + (threadIdx.x >> 7)) * 8;
    const int p  = half * 1152 + pc * 128 + (threadIdx.x & 127);

    const float* in   = stream ? a_ir : a_rgb;
    const float* w    = stream ? pi_w : pr_w;
    const float* bias = stream ? pi_b : pr_b;
    float*       out  = stream ? c_ir : c_rgb;
    const float* ip = in + (size_t)bb * kInner * kP + p;
    float acc[8];
    #pragma unroll
    for (int r = 0; r < 8; ++r) acc[r] = bias[ot + r];
    #pragma unroll 4
    for (int c = 0; c < kInner; c += 4) {
        float v[4];
        #pragma unroll
        for (int j = 0; j < 4; ++j) v[j] = ip[(size_t)(c + j) * kP];
        #pragma unroll
        for (int r = 0; r < 8; ++r) {
            const float4 w4 = *(const float4*)(w + (size_t)(ot + r) * kInner + c);
            const float* ww = (const float*)&w4;
            #pragma unroll
            for (int j = 0; j < 4; ++j) acc[r] = fmaf(ww[j], v[j], acc[r]);
        }
    }
    float* op = out + ((size_t)bb * kDim + ot) * kP + p;
    #pragma unroll
    for (int r = 0; r < 8; ++r) op[(size_t)r * kP] = acc[r];
}

// ---------------- gate + residual (C=512 -> O=256), both streams.
// XCD-affine 1-D grid (1152): id&7 -> (stream,bb,half), id>>3 -> (o-tile, pos-chunk).
// Block: 128 positions x 2 o-groups; 8 outputs/thread (16 per block).
__global__ __launch_bounds__(256) void gate_conv(
    const float* __restrict__ f_rgb, const float* __restrict__ f_ir,
    const float* __restrict__ c_rgb, const float* __restrict__ c_ir,
    const float* __restrict__ gr_w, const float* __restrict__ gr_b,
    const float* __restrict__ gi_w, const float* __restrict__ gi_b,
    float* __restrict__ out_rgb, float* __restrict__ out_ir)
{
    const int fid = blockIdx.x;              // 0..1151
    const int xcd = fid & 7, q = fid >> 3;   // q 0..143
    const int stream = (xcd >> 2) & 1, bb = (xcd >> 1) & 1, half = xcd & 1;
    const int ot = (q & 15) * 16 + (threadIdx.x >> 7) * 8;   // 16 o-tiles of 16
    const int pc = q >> 4;                   // 0..8
    const int p  = half * 1152 + pc * 128 + (threadIdx.x & 127);

    const float* f    = stream ? f_ir  : f_rgb;
    const float* cr   = stream ? c_ir  : c_rgb;
    const float* w    = stream ? gi_w  : gr_w;
    const float* bias = stream ? gi_b  : gr_b;
    float*       out  = stream ? out_ir : out_rgb;
    const float* fb = f  + (size_t)bb * kDim * kP + p;
    const float* cb = cr + (size_t)bb * kDim * kP + p;
    float acc[8];
    #pragma unroll
    for (int r = 0; r < 8; ++r) acc[r] = bias[ot + r];
    #pragma unroll 4
    for (int c = 0; c < kDim; c += 4) {
        float v[4];
        #pragma unroll
        for (int j = 0; j < 4; ++j) v[j] = fb[(size_t)(c + j) * kP];
        #pragma unroll
        for (int r = 0; r < 8; ++r) {
            const float4 w4 = *(const float4*)(w + (size_t)(ot + r) * (2 * kDim) + c);
            const float* ww = (const float*)&w4;
            #pragma unroll
            for (int j = 0; j < 4; ++j) acc[r] = fmaf(ww[j], v[j], acc[r]);
        }
    }
    #pragma unroll 4
    for (int c = 0; c < kDim; c += 4) {
        float v[4];
        #pragma unroll
        for (int j = 0; j < 4; ++j) v[j] = cb[(size_t)(c + j) * kP];
        #pragma unroll
        for (int r = 0; r < 8; ++r) {
            const float4 w4 = *(const float4*)(w + (size_t)(ot + r) * (2 * kDim) + kDim + c);
            const float* ww = (const float*)&w4;
            #pragma unroll
            for (int j = 0; j < 4; ++j) acc[r] = fmaf(ww[j], v[j], acc[r]);
        }
    }
    float* op = out + ((size_t)bb * kDim + ot) * kP + p;
    #pragma unroll
    for (int r = 0; r < 8; ++r) {
        const float gt = 1.f / (1.f + __expf(-acc[r]));
        op[(size_t)r * kP] = fb[(size_t)(ot + r) * kP] + gt * cb[(size_t)(ot + r) * kP];
    }
}

extern "C" void kernel_launch(void* const* d_in, const int* in_sizes, int n_in,
                              void* d_out, int out_size, void* d_ws, size_t ws_size,
                              hipStream_t stream)
{
    const float* f_rgb  = (const float*)d_in[0];
    const float* f_ir   = (const float*)d_in[1];
    const float* nr_w   = (const float*)d_in[2];
    const float* nr_b   = (const float*)d_in[3];
    const float* ni_w   = (const float*)d_in[4];
    const float* ni_b   = (const float*)d_in[5];
    const float* qr_w   = (const float*)d_in[6];
    const float* qr_b   = (const float*)d_in[7];
    const float* kvi_w  = (const float*)d_in[8];
    const float* kvi_b  = (const float*)d_in[9];
    const float* qi_w   = (const float*)d_in[10];
    const float* qi_b   = (const float*)d_in[11];
    const float* kvr_w  = (const float*)d_in[12];
    const float* kvr_b  = (const float*)d_in[13];
    const float* pr_w   = (const float*)d_in[14];
    const float* pr_b   = (const float*)d_in[15];
    const float* pr_lnw = (const float*)d_in[16];
    const float* pr_lnb = (const float*)d_in[17];
    const float* pi_w   = (const float*)d_in[18];
    const float* pi_b   = (const float*)d_in[19];
    const float* pi_lnw = (const float*)d_in[20];
    const float* pi_lnb = (const float*)d_in[21];
    const float* gr_w   = (const float*)d_in[22];
    const float* gr_b   = (const float*)d_in[23];
    const float* gi_w   = (const float*)d_in[24];
    const float* gi_b   = (const float*)d_in[25];

    // workspace layout (floats)
    float* ws    = (float*)d_ws;
    float* n_rgb = ws;                        // 1179648
    float* n_ir  = n_rgb + 1179648;           // 1179648
    float* fp16base = n_ir + 1179648;         // 6 x 147456 floats (f16 arrays)
    _Float16* q_r  = (_Float16*)(fp16base);
    _Float16* k_r  = (_Float16*)(fp16base + 1 * 147456);
    _Float16* vt_r = (_Float16*)(fp16base + 2 * 147456);
    _Float16* q_i  = (_Float16*)(fp16base + 3 * 147456);
    _Float16* k_i  = (_Float16*)(fp16base + 4 * 147456);
    _Float16* vt_i = (_Float16*)(fp16base + 5 * 147456);
    float* a_rgb = fp16base + 6 * 147456;     // 294912
    float* a_ir  = a_rgb + 294912;            // 294912
    float* c_rgb = n_rgb;                     // reuse after projections
    float* c_ir  = n_ir;

    float* out_rgb = (float*)d_out;
    float* out_ir  = out_rgb + (size_t)kB * kDim * kP;

    const dim3 blk(256);

    // 1) LN of both inputs (one launch)
    ln2_kernel<<<dim3(288, 2), blk, 0, stream>>>(f_rgb, nr_w, nr_b, n_rgb,
                                                 f_ir,  ni_w, ni_b, n_ir);
    // 2) all q/kv projections (one launch, XCD-affine)
    qkv_conv<<<dim3(864), blk, 0, stream>>>(n_rgb, n_ir,
                                            qr_w, qr_b, kvr_w, kvr_b,
                                            qi_w, qi_b, kvi_w, kvi_b,
                                            q_r, k_r, vt_r, q_i, k_i, vt_i);
    // 3) fused MFMA attention (both streams, one launch)
    attn_mfma<<<dim3(36, 16, 2), blk, 0, stream>>>(q_r, k_i, vt_i, q_i, k_r, vt_r,
                                                   a_rgb, a_ir);
    // 4) output projection + LN
    proj_conv<<<dim3(1152), blk, 0, stream>>>(a_rgb, a_ir, pr_w, pr_b, pi_w, pi_b,
                                              c_rgb, c_ir);
    ln2_kernel<<<dim3(288, 2), blk, 0, stream>>>(c_rgb, pr_lnw, pr_lnb, c_rgb,
                                                 c_ir,  pi_lnw, pi_lnb, c_ir);
    // 5) gate + residual (XCD-affine)
    gate_conv<<<dim3(1152), blk, 0, stream>>>(f_rgb, f_ir, c_rgb, c_ir,
                                              gr_w, gr_b, gi_w, gi_b,
                                              out_rgb, out_ir);
}

// Round 8
// 194.595 us; speedup vs baseline: 1.6714x; 1.6714x over previous
//
#include <hip/hip_runtime.h>

static constexpr int kDim   = 256;
static constexpr int kInner = 64;
static constexpr int kNH    = 8;
static constexpr int kHD    = 8;
static constexpr int kB     = 2;
static constexpr int kP     = 2304;   // 48*48
static constexpr float kScale = 0.35355339059327373f; // 8^-0.5
static constexpr float kEps   = 1e-6f;

typedef _Float16 half4f __attribute__((ext_vector_type(4)));
typedef float    f32x4  __attribute__((ext_vector_type(4)));

// ---------------- LayerNorm over channels (C=256), both images in one launch.
__global__ __launch_bounds__(256) void ln2_kernel(
    const float* __restrict__ x0, const float* __restrict__ w0,
    const float* __restrict__ b0, float* __restrict__ o0,
    const float* __restrict__ x1, const float* __restrict__ w1,
    const float* __restrict__ b1, float* __restrict__ o1)
{
    __shared__ float sb[16][16];
    __shared__ float ssb[16][16];
    const float* x = blockIdx.y ? x1 : x0;
    const float* w = blockIdx.y ? w1 : w0;
    const float* b = blockIdx.y ? b1 : b0;
    float*       o = blockIdx.y ? o1 : o0;
    const int pos = threadIdx.x & 15;
    const int grp = threadIdx.x >> 4;
    const int idx = blockIdx.x * 16 + pos;
    const int bb  = idx / kP;
    const int p   = idx - bb * kP;
    const size_t base = (size_t)bb * kDim * kP + p;
    const int c0 = grp * 16;

    float v[16];
    float s = 0.f, ss = 0.f;
    #pragma unroll
    for (int j = 0; j < 16; ++j) {
        v[j] = x[base + (size_t)(c0 + j) * kP];
        s += v[j]; ss += v[j] * v[j];
    }
    sb[grp][pos] = s; ssb[grp][pos] = ss;
    __syncthreads();
    float st = 0.f, sst = 0.f;
    #pragma unroll
    for (int g = 0; g < 16; ++g) { st += sb[g][pos]; sst += ssb[g][pos]; }
    const float mean = st * (1.f / kDim);
    const float rstd = rsqrtf(sst * (1.f / kDim) - mean * mean + kEps);
    #pragma unroll
    for (int j = 0; j < 16; ++j)
        o[base + (size_t)(c0 + j) * kP] = (v[j] - mean) * rstd * w[c0 + j] + b[c0 + j];
}

// ---------------- fused q/kv projections (C=256) -> f16 outputs for MFMA attn.
// XCD-affine 1-D grid (864): id&7 -> (inp,bb,half), id>>3 -> (tile-pair, pos-chunk).
// og forced into SGPR via readfirstlane so weight loads stay on the scalar path.
__global__ __launch_bounds__(256) void qkv_conv(
    const float* __restrict__ n_rgb, const float* __restrict__ n_ir,
    const float* __restrict__ qr_w, const float* __restrict__ qr_b,
    const float* __restrict__ kvr_w, const float* __restrict__ kvr_b,
    const float* __restrict__ qi_w, const float* __restrict__ qi_b,
    const float* __restrict__ kvi_w, const float* __restrict__ kvi_b,
    _Float16* __restrict__ q_r, _Float16* __restrict__ k_r, _Float16* __restrict__ vt_r,
    _Float16* __restrict__ q_i, _Float16* __restrict__ k_i, _Float16* __restrict__ vt_i)
{
    const int f    = blockIdx.x;             // 0..863
    const int xcd  = f & 7, q = f >> 3;      // q 0..107
    const int inp  = (xcd >> 2) & 1, bb = (xcd >> 1) & 1, half = xcd & 1;
    const int tp   = q % 12, pc = q / 12;    // 12 tile-pairs, 9 pos-chunks
    const int og   = __builtin_amdgcn_readfirstlane(threadIdx.x >> 7);  // wave-uniform
    const int tile = tp * 2 + og;            // 0..23
    const int p    = half * 1152 + pc * 128 + (threadIdx.x & 127);

    const float* in = inp ? n_ir : n_rgb;
    const float* w; const float* bias;
    if (tile < 8) { w = inp ? qi_w : qr_w;   bias = inp ? qi_b : qr_b;
                    w += (size_t)tile * 8 * kDim; bias += tile * 8; }
    else          { const int t = tile - 8;
                    w = inp ? kvi_w : kvr_w; bias = inp ? kvi_b : kvr_b;
                    w += (size_t)t * 8 * kDim; bias += t * 8; }
    const float* ip = in + (size_t)bb * kDim * kP + p;
    float acc[8];
    #pragma unroll
    for (int r = 0; r < 8; ++r) acc[r] = bias[r];
    #pragma unroll 4
    for (int c = 0; c < kDim; c += 4) {
        float v[4];
        #pragma unroll
        for (int j = 0; j < 4; ++j) v[j] = ip[(size_t)(c + j) * kP];
        #pragma unroll
        for (int r = 0; r < 8; ++r) {
            const float4 w4 = *(const float4*)(w + (size_t)r * kDim + c);
            const float* ww = (const float*)&w4;
            #pragma unroll
            for (int j = 0; j < 4; ++j) acc[r] = fmaf(ww[j], v[j], acc[r]);
        }
    }
    if (tile < 8) {                       // Q (scaled), pos-major
        _Float16* qp = (inp ? q_i : q_r) + ((size_t)(bb * kNH + tile) * kP + p) * 8;
        half4f lo = { (_Float16)(acc[0]*kScale), (_Float16)(acc[1]*kScale),
                      (_Float16)(acc[2]*kScale), (_Float16)(acc[3]*kScale) };
        half4f hi = { (_Float16)(acc[4]*kScale), (_Float16)(acc[5]*kScale),
                      (_Float16)(acc[6]*kScale), (_Float16)(acc[7]*kScale) };
        *(half4f*)qp = lo; *(half4f*)(qp + 4) = hi;
    } else if (tile < 16) {               // K, pos-major
        const int h = tile - 8;
        _Float16* kp = (inp ? k_i : k_r) + ((size_t)(bb * kNH + h) * kP + p) * 8;
        half4f lo = { (_Float16)acc[0], (_Float16)acc[1], (_Float16)acc[2], (_Float16)acc[3] };
        half4f hi = { (_Float16)acc[4], (_Float16)acc[5], (_Float16)acc[6], (_Float16)acc[7] };
        *(half4f*)kp = lo; *(half4f*)(kp + 4) = hi;
    } else {                              // V, transposed [bh][8][P]
        const int h = tile - 16;
        _Float16* vp = (inp ? vt_i : vt_r) + (size_t)(bb * kNH + h) * 8 * kP + p;
        #pragma unroll
        for (int d = 0; d < 8; ++d) vp[(size_t)d * kP] = (_Float16)acc[d];
    }
}

// ---------------- fused MFMA flash attention (both streams).
// grid (36, 16, 2): x = q-tile of 64, y = bh, z = stream. block 256 = 4 waves x 16 q.
__global__ __launch_bounds__(256) void attn_mfma(
    const _Float16* __restrict__ q0, const _Float16* __restrict__ k0, const _Float16* __restrict__ vt0,
    const _Float16* __restrict__ q1, const _Float16* __restrict__ k1, const _Float16* __restrict__ vt1,
    float* __restrict__ a0, float* __restrict__ a1)
{
    __shared__ _Float16 Ksm[256 * 24];   // 48B rows: halfs 0..7 = K[d], 8..15 = zeros
    __shared__ _Float16 Vsm[16 * 264];   // rows d (8 real + 8 zero), 264-half pitch
    const _Float16* Qg = blockIdx.z ? q1  : q0;
    const _Float16* Kg = blockIdx.z ? k1  : k0;
    const _Float16* Vg = blockIdx.z ? vt1 : vt0;
    float*          Ag = blockIdx.z ? a1  : a0;
    const int bh = blockIdx.y;
    const int bb = bh >> 3, h = bh & 7;
    const int tid  = threadIdx.x;
    const int wv   = tid >> 6;
    const int lane = tid & 63;
    const int r16  = lane & 15;
    const int g    = lane >> 4;

    {
        const float4 z4 = make_float4(0.f, 0.f, 0.f, 0.f);
        *(float4*)(Ksm + tid * 24 + 8) = z4;
        for (int i = tid; i < 264; i += 256)
            *(float4*)(Vsm + 8 * 264 + i * 8) = z4;
    }

    const int qg = blockIdx.x * 64 + wv * 16 + r16;
    half4f qf = (half4f){0, 0, 0, 0};
    if (g < 2) qf = *(const half4f*)(Qg + ((size_t)bh * kP + qg) * 8 + g * 4);

    f32x4 of = (f32x4){0.f, 0.f, 0.f, 0.f};
    float rs = 0.f;

    for (int ch = 0; ch < 9; ++ch) {
        if (ch) __syncthreads();
        const int p0 = ch * 256;
        *(float4*)(Ksm + tid * 24) = *(const float4*)(Kg + ((size_t)bh * kP + p0 + tid) * 8);
        {
            const int d = tid >> 5, c8 = (tid & 31) * 8;
            *(float4*)(Vsm + d * 264 + c8) =
                *(const float4*)(Vg + ((size_t)(bh * 8 + d)) * kP + p0 + c8);
        }
        __syncthreads();
        #pragma unroll
        for (int kt = 0; kt < 16; ++kt) {
            const half4f kf = *(const half4f*)(Ksm + (kt * 16 + r16) * 24 + g * 4);
            f32x4 s = __builtin_amdgcn_mfma_f32_16x16x16f16(kf, qf, (f32x4){0.f,0.f,0.f,0.f}, 0, 0, 0);
            const float e0 = __expf(s[0]), e1 = __expf(s[1]);
            const float e2 = __expf(s[2]), e3 = __expf(s[3]);
            rs += (e0 + e1) + (e2 + e3);
            const half4f pf = { (_Float16)e0, (_Float16)e1, (_Float16)e2, (_Float16)e3 };
            const half4f vf = *(const half4f*)(Vsm + r16 * 264 + kt * 16 + g * 4);
            of = __builtin_amdgcn_mfma_f32_16x16x16f16(vf, pf, of, 0, 0, 0);
        }
    }
    rs += __shfl_xor(rs, 16, 64);
    rs += __shfl_xor(rs, 32, 64);
    const float inv = 1.f / rs;
    if (g < 2) {
        float* op = Ag + ((size_t)(bb * kInner + h * 8 + g * 4)) * kP + qg;
        #pragma unroll
        for (int i = 0; i < 4; ++i) op[(size_t)i * kP] = of[i] * inv;
    }
}

// ---------------- output projection (C=64 -> O=256), both streams.
// XCD-affine 1-D grid (1152): id&7 -> (stream,bb,half), id>>3 -> (tile-pair, pos-chunk).
__global__ __launch_bounds__(256) void proj_conv(
    const float* __restrict__ a_rgb, const float* __restrict__ a_ir,
    const float* __restrict__ pr_w, const float* __restrict__ pr_b,
    const float* __restrict__ pi_w, const float* __restrict__ pi_b,
    float* __restrict__ c_rgb, float* __restrict__ c_ir)
{
    const int f   = blockIdx.x;              // 0..1151
    const int xcd = f & 7, q = f >> 3;       // q 0..143
    const int stream = (xcd >> 2) & 1, bb = (xcd >> 1) & 1, half = xcd & 1;
    const int tp = q & 15, pc = q >> 4;      // 16 tile-pairs, 9 pos-chunks
    const int og = __builtin_amdgcn_readfirstlane(threadIdx.x >> 7);  // wave-uniform
    const int ot = (tp * 2 + og) * 8;
    const int p  = half * 1152 + pc * 128 + (threadIdx.x & 127);

    const float* in   = stream ? a_ir : a_rgb;
    const float* w    = stream ? pi_w : pr_w;
    const float* bias = stream ? pi_b : pr_b;
    float*       out  = stream ? c_ir : c_rgb;
    const float* ip = in + (size_t)bb * kInner * kP + p;
    float acc[8];
    #pragma unroll
    for (int r = 0; r < 8; ++r) acc[r] = bias[ot + r];
    #pragma unroll 4
    for (int c = 0; c < kInner; c += 4) {
        float v[4];
        #pragma unroll
        for (int j = 0; j < 4; ++j) v[j] = ip[(size_t)(c + j) * kP];
        #pragma unroll
        for (int r = 0; r < 8; ++r) {
            const float4 w4 = *(const float4*)(w + (size_t)(ot + r) * kInner + c);
            const float* ww = (const float*)&w4;
            #pragma unroll
            for (int j = 0; j < 4; ++j) acc[r] = fmaf(ww[j], v[j], acc[r]);
        }
    }
    float* op = out + ((size_t)bb * kDim + ot) * kP + p;
    #pragma unroll
    for (int r = 0; r < 8; ++r) op[(size_t)r * kP] = acc[r];
}

// ---------------- gate + residual (C=512 -> O=256), both streams.
// XCD-affine 1-D grid (1152): id&7 -> (stream,bb,half), id>>3 -> (o-tile, pos-chunk).
__global__ __launch_bounds__(256) void gate_conv(
    const float* __restrict__ f_rgb, const float* __restrict__ f_ir,
    const float* __restrict__ c_rgb, const float* __restrict__ c_ir,
    const float* __restrict__ gr_w, const float* __restrict__ gr_b,
    const float* __restrict__ gi_w, const float* __restrict__ gi_b,
    float* __restrict__ out_rgb, float* __restrict__ out_ir)
{
    const int fid = blockIdx.x;              // 0..1151
    const int xcd = fid & 7, q = fid >> 3;   // q 0..143
    const int stream = (xcd >> 2) & 1, bb = (xcd >> 1) & 1, half = xcd & 1;
    const int og = __builtin_amdgcn_readfirstlane(threadIdx.x >> 7);  // wave-uniform
    const int ot = (q & 15) * 16 + og * 8;   // 16 o-tiles of 16
    const int pc = q >> 4;                   // 0..8
    const int p  = half * 1152 + pc * 128 + (threadIdx.x & 127);

    const float* f    = stream ? f_ir  : f_rgb;
    const float* cr   = stream ? c_ir  : c_rgb;
    const float* w    = stream ? gi_w  : gr_w;
    const float* bias = stream ? gi_b  : gr_b;
    float*       out  = stream ? out_ir : out_rgb;
    const float* fb = f  + (size_t)bb * kDim * kP + p;
    const float* cb = cr + (size_t)bb * kDim * kP + p;
    float acc[8];
    #pragma unroll
    for (int r = 0; r < 8; ++r) acc[r] = bias[ot + r];
    #pragma unroll 4
    for (int c = 0; c < kDim; c += 4) {
        float v[4];
        #pragma unroll
        for (int j = 0; j < 4; ++j) v[j] = fb[(size_t)(c + j) * kP];
        #pragma unroll
        for (int r = 0; r < 8; ++r) {
            const float4 w4 = *(const float4*)(w + (size_t)(ot + r) * (2 * kDim) + c);
            const float* ww = (const float*)&w4;
            #pragma unroll
            for (int j = 0; j < 4; ++j) acc[r] = fmaf(ww[j], v[j], acc[r]);
        }
    }
    #pragma unroll 4
    for (int c = 0; c < kDim; c += 4) {
        float v[4];
        #pragma unroll
        for (int j = 0; j < 4; ++j) v[j] = cb[(size_t)(c + j) * kP];
        #pragma unroll
        for (int r = 0; r < 8; ++r) {
            const float4 w4 = *(const float4*)(w + (size_t)(ot + r) * (2 * kDim) + kDim + c);
            const float* ww = (const float*)&w4;
            #pragma unroll
            for (int j = 0; j < 4; ++j) acc[r] = fmaf(ww[j], v[j], acc[r]);
        }
    }
    float* op = out + ((size_t)bb * kDim + ot) * kP + p;
    #pragma unroll
    for (int r = 0; r < 8; ++r) {
        const float gt = 1.f / (1.f + __expf(-acc[r]));
        op[(size_t)r * kP] = fb[(size_t)(ot + r) * kP] + gt * cb[(size_t)(ot + r) * kP];
    }
}

extern "C" void kernel_launch(void* const* d_in, const int* in_sizes, int n_in,
                              void* d_out, int out_size, void* d_ws, size_t ws_size,
                              hipStream_t stream)
{
    const float* f_rgb  = (const float*)d_in[0];
    const float* f_ir   = (const float*)d_in[1];
    const float* nr_w   = (const float*)d_in[2];
    const float* nr_b   = (const float*)d_in[3];
    const float* ni_w   = (const float*)d_in[4];
    const float* ni_b   = (const float*)d_in[5];
    const float* qr_w   = (const float*)d_in[6];
    const float* qr_b   = (const float*)d_in[7];
    const float* kvi_w  = (const float*)d_in[8];
    const float* kvi_b  = (const float*)d_in[9];
    const float* qi_w   = (const float*)d_in[10];
    const float* qi_b   = (const float*)d_in[11];
    const float* kvr_w  = (const float*)d_in[12];
    const float* kvr_b  = (const float*)d_in[13];
    const float* pr_w   = (const float*)d_in[14];
    const float* pr_b   = (const float*)d_in[15];
    const float* pr_lnw = (const float*)d_in[16];
    const float* pr_lnb = (const float*)d_in[17];
    const float* pi_w   = (const float*)d_in[18];
    const float* pi_b   = (const float*)d_in[19];
    const float* pi_lnw = (const float*)d_in[20];
    const float* pi_lnb = (const float*)d_in[21];
    const float* gr_w   = (const float*)d_in[22];
    const float* gr_b   = (const float*)d_in[23];
    const float* gi_w   = (const float*)d_in[24];
    const float* gi_b   = (const float*)d_in[25];

    // workspace layout (floats)
    float* ws    = (float*)d_ws;
    float* n_rgb = ws;                        // 1179648
    float* n_ir  = n_rgb + 1179648;           // 1179648
    float* fp16base = n_ir + 1179648;         // 6 x 147456 floats (f16 arrays)
    _Float16* q_r  = (_Float16*)(fp16base);
    _Float16* k_r  = (_Float16*)(fp16base + 1 * 147456);
    _Float16* vt_r = (_Float16*)(fp16base + 2 * 147456);
    _Float16* q_i  = (_Float16*)(fp16base + 3 * 147456);
    _Float16* k_i  = (_Float16*)(fp16base + 4 * 147456);
    _Float16* vt_i = (_Float16*)(fp16base + 5 * 147456);
    float* a_rgb = fp16base + 6 * 147456;     // 294912
    float* a_ir  = a_rgb + 294912;            // 294912
    float* c_rgb = n_rgb;                     // reuse after projections
    float* c_ir  = n_ir;

    float* out_rgb = (float*)d_out;
    float* out_ir  = out_rgb + (size_t)kB * kDim * kP;

    const dim3 blk(256);

    // 1) LN of both inputs (one launch)
    ln2_kernel<<<dim3(288, 2), blk, 0, stream>>>(f_rgb, nr_w, nr_b, n_rgb,
                                                 f_ir,  ni_w, ni_b, n_ir);
    // 2) all q/kv projections (one launch, XCD-affine)
    qkv_conv<<<dim3(864), blk, 0, stream>>>(n_rgb, n_ir,
                                            qr_w, qr_b, kvr_w, kvr_b,
                                            qi_w, qi_b, kvi_w, kvi_b,
                                            q_r, k_r, vt_r, q_i, k_i, vt_i);
    // 3) fused MFMA attention (both streams, one launch)
    attn_mfma<<<dim3(36, 16, 2), blk, 0, stream>>>(q_r, k_i, vt_i, q_i, k_r, vt_r,
                                                   a_rgb, a_ir);
    // 4) output projection + LN
    proj_conv<<<dim3(1152), blk, 0, stream>>>(a_rgb, a_ir, pr_w, pr_b, pi_w, pi_b,
                                              c_rgb, c_ir);
    ln2_kernel<<<dim3(288, 2), blk, 0, stream>>>(c_rgb, pr_lnw, pr_lnb, c_rgb,
                                                 c_ir,  pi_lnw, pi_lnb, c_ir);
    // 5) gate + residual (XCD-affine)
    gate_conv<<<dim3(1152), blk, 0, stream>>>(f_rgb, f_ir, c_rgb, c_ir,
                                              gr_w, gr_b, gi_w, gi_b,
                                              out_rgb, out_ir);
}

// Round 9
// 130.742 us; speedup vs baseline: 2.4877x; 1.4884x over previous
//
#include <hip/hip_runtime.h>

static constexpr int kDim   = 256;
static constexpr int kInner = 64;
static constexpr int kNH    = 8;
static constexpr int kB     = 2;
static constexpr int kP     = 2304;   // 48*48
static constexpr float kScale = 0.35355339059327373f; // 8^-0.5
static constexpr float kEps   = 1e-6f;

typedef _Float16 half4f __attribute__((ext_vector_type(4)));
typedef _Float16 half8  __attribute__((ext_vector_type(8)));
typedef float    f32x4  __attribute__((ext_vector_type(4)));

// ws layout in halfs:
static constexpr size_t oXq  = 0;          // [4 combo][2304][256]      = 2359296
static constexpr size_t oQ16 = 2359296;    // [2 inp][16 bh][2304][8]   = 589824
static constexpr size_t oK16 = 2949120;    // same                      = 589824
static constexpr size_t oV16 = 3538944;    // [2 inp][16 bh][8][2304]   = 589824
static constexpr size_t oA16 = 4128768;    // [4 combo][2304][64]       = 589824
// Xg aliases [0 .. 4718592): [4 combo][2304][512]  (written after all above dead)
static constexpr size_t oC16 = 4718592;    // [4 combo][2304][256]      = 2359296
static constexpr size_t oW16 = 7077888;    // weights f16               = 393216
static constexpr size_t kInpStride = 294912; // q16/k16/vt16 per-inp stride (halfs)

// ---------------- weight f32 -> f16 cast (8 segments). grid (64, 8).
__global__ __launch_bounds__(256) void wcast(
    const float* __restrict__ qr_w, const float* __restrict__ kvr_w,
    const float* __restrict__ qi_w, const float* __restrict__ kvi_w,
    const float* __restrict__ pr_w, const float* __restrict__ pi_w,
    const float* __restrict__ gr_w, const float* __restrict__ gi_w,
    _Float16* __restrict__ w16)    // base at oW16
{
    const float* src; _Float16* dst; int n;
    _Float16* Aq = w16;             // [2][192][256]
    _Float16* Ap = w16 + 98304;     // [2][256][64]
    _Float16* Ag = w16 + 131072;    // [2][256][512]
    switch (blockIdx.y) {
        case 0: src = qr_w;  dst = Aq;          n = 16384;  break;
        case 1: src = kvr_w; dst = Aq + 16384;  n = 32768;  break;
        case 2: src = qi_w;  dst = Aq + 49152;  n = 16384;  break;
        case 3: src = kvi_w; dst = Aq + 65536;  n = 32768;  break;
        case 4: src = pr_w;  dst = Ap;          n = 16384;  break;
        case 5: src = pi_w;  dst = Ap + 16384;  n = 16384;  break;
        case 6: src = gr_w;  dst = Ag;          n = 131072; break;
        default:src = gi_w;  dst = Ag + 131072; n = 131072; break;
    }
    for (int i = blockIdx.x * 256 + threadIdx.x; i < n; i += 64 * 256)
        dst[i] = (_Float16)src[i];
}

// ---------------- pre-LN: f32 [c][p] -> f16 Xq [combo][p][256]. grid (288, 2).
__global__ __launch_bounds__(256) void ln_pre(
    const float* __restrict__ x0, const float* __restrict__ w0,
    const float* __restrict__ b0, const float* __restrict__ x1,
    const float* __restrict__ w1, const float* __restrict__ b1,
    _Float16* __restrict__ Xq)
{
    __shared__ float sb[16][16];
    __shared__ float ssb[16][16];
    const int inp = blockIdx.y;
    const float* x = inp ? x1 : x0;
    const float* w = inp ? w1 : w0;
    const float* b = inp ? b1 : b0;
    const int pos = threadIdx.x & 15;
    const int grp = threadIdx.x >> 4;
    const int idx = blockIdx.x * 16 + pos;
    const int bb  = idx / kP;
    const int p   = idx - bb * kP;
    const size_t base = (size_t)bb * kDim * kP + p;
    const int c0 = grp * 16;

    float v[16];
    float s = 0.f, ss = 0.f;
    #pragma unroll
    for (int j = 0; j < 16; ++j) {
        v[j] = x[base + (size_t)(c0 + j) * kP];
        s += v[j]; ss += v[j] * v[j];
    }
    sb[grp][pos] = s; ssb[grp][pos] = ss;
    __syncthreads();
    float st = 0.f, sst = 0.f;
    #pragma unroll
    for (int g = 0; g < 16; ++g) { st += sb[g][pos]; sst += ssb[g][pos]; }
    const float mean = st * (1.f / kDim);
    const float rstd = rsqrtf(sst * (1.f / kDim) - mean * mean + kEps);
    half8 h0, h1;
    #pragma unroll
    for (int j = 0; j < 8; ++j) {
        h0[j] = (_Float16)((v[j]     - mean) * rstd * w[c0 + j]     + b[c0 + j]);
        h1[j] = (_Float16)((v[j + 8] - mean) * rstd * w[c0 + j + 8] + b[c0 + j + 8]);
    }
    _Float16* dst = Xq + ((size_t)(inp * 2 + bb) * kP + p) * 256 + c0;
    *(half8*)dst       = h0;
    *(half8*)(dst + 8) = h1;
}

// ---------------- post-LN: c16 [combo][p][256] -> LN -> Xg[combo][p][256..512);
// also casts raw f (f32 [c][p]) into Xg[combo][p][0..256). grid (288, 2): y = stream.
__global__ __launch_bounds__(256) void ln_post(
    const _Float16* __restrict__ c16,
    const float* __restrict__ w0, const float* __restrict__ b0,
    const float* __restrict__ w1, const float* __restrict__ b1,
    const float* __restrict__ f0, const float* __restrict__ f1,
    _Float16* __restrict__ Xg)
{
    __shared__ float sb[16][16];
    __shared__ float ssb[16][16];
    const int s = blockIdx.y;
    const float* w = s ? w1 : w0;
    const float* b = s ? b1 : b0;
    const float* F = s ? f1 : f0;
    const int pos = threadIdx.x & 15;
    const int grp = threadIdx.x >> 4;
    const int idx = blockIdx.x * 16 + pos;
    const int bb  = idx / kP;
    const int p   = idx - bb * kP;
    const int c0  = grp * 16;
    const size_t combo = s * 2 + bb;

    const _Float16* cp = c16 + (combo * kP + p) * 256 + c0;
    const half8 g0 = *(const half8*)cp;
    const half8 g1 = *(const half8*)(cp + 8);
    float v[16];
    float sm = 0.f, ssq = 0.f;
    #pragma unroll
    for (int j = 0; j < 8; ++j) {
        v[j] = (float)g0[j]; v[j + 8] = (float)g1[j];
    }
    #pragma unroll
    for (int j = 0; j < 16; ++j) { sm += v[j]; ssq += v[j] * v[j]; }
    sb[grp][pos] = sm; ssb[grp][pos] = ssq;
    __syncthreads();
    float st = 0.f, sst = 0.f;
    #pragma unroll
    for (int g = 0; g < 16; ++g) { st += sb[g][pos]; sst += ssb[g][pos]; }
    const float mean = st * (1.f / kDim);
    const float rstd = rsqrtf(sst * (1.f / kDim) - mean * mean + kEps);

    _Float16* xrow = Xg + (combo * kP + p) * 512;
    half8 o0, o1;
    #pragma unroll
    for (int j = 0; j < 8; ++j) {
        o0[j] = (_Float16)((v[j]     - mean) * rstd * w[c0 + j]     + b[c0 + j]);
        o1[j] = (_Float16)((v[j + 8] - mean) * rstd * w[c0 + j + 8] + b[c0 + j + 8]);
    }
    *(half8*)(xrow + 256 + c0)     = o0;
    *(half8*)(xrow + 256 + c0 + 8) = o1;
    // raw f -> first half
    const size_t fbase = (size_t)bb * kDim * kP + p;
    half8 r0, r1;
    #pragma unroll
    for (int j = 0; j < 8; ++j) {
        r0[j] = (_Float16)F[fbase + (size_t)(c0 + j) * kP];
        r1[j] = (_Float16)F[fbase + (size_t)(c0 + j + 8) * kP];
    }
    *(half8*)(xrow + c0)     = r0;
    *(half8*)(xrow + c0 + 8) = r1;
}

// ---------------- generic f16 MFMA GEMM: C[o,p] = sum_c A[s][o][c] * B[combo][p][c].
// XCD-affine flat grid: fid&7 -> (s, bb, half); fid>>3 -> (o-tile16, p-tile64).
// EPI: 0 = qkv (route q/k/vt f16), 1 = proj (c16 f16), 2 = gate (sigmoid+residual f32).
template <int M, int K, int EPI>
__global__ __launch_bounds__(256) void gemm_f16(
    const _Float16* __restrict__ A,     // [2][M][K] f16 weights
    const _Float16* __restrict__ B,     // [4][2304][K] f16 activations
    const float* __restrict__ b0, const float* __restrict__ b1,
    const float* __restrict__ b2, const float* __restrict__ b3,
    _Float16* __restrict__ o16a, _Float16* __restrict__ o16b, _Float16* __restrict__ o16c,
    const float* __restrict__ f0, const float* __restrict__ f1,
    float* __restrict__ outp)
{
    const int fid = blockIdx.x;
    const int xcd = fid & 7, q = fid >> 3;
    const int s = (xcd >> 2) & 1, bb = (xcd >> 1) & 1, half = xcd & 1;
    constexpr int MT = M / 16;
    const int ot = (q % MT) * 16;
    const int pt = q / MT;                     // 0..17
    const int wv = threadIdx.x >> 6, lane = threadIdx.x & 63;
    const int r16 = lane & 15, g = lane >> 4;
    const int p = half * 1152 + pt * 64 + wv * 16 + r16;
    const int combo = s * 2 + bb;

    const _Float16* Ar = A + ((size_t)s * M + ot + r16) * K + 8 * g;
    const _Float16* Br = B + ((size_t)combo * kP + p) * K + 8 * g;
    f32x4 acc0 = {0.f, 0.f, 0.f, 0.f}, acc1 = {0.f, 0.f, 0.f, 0.f};
    #pragma unroll
    for (int c0 = 0; c0 < K; c0 += 32) {
        const half8 a8 = *(const half8*)(Ar + c0);
        const half8 b8 = *(const half8*)(Br + c0);
        const half4f al = {a8[0], a8[1], a8[2], a8[3]};
        const half4f ah = {a8[4], a8[5], a8[6], a8[7]};
        const half4f bl = {b8[0], b8[1], b8[2], b8[3]};
        const half4f bh = {b8[4], b8[5], b8[6], b8[7]};
        acc0 = __builtin_amdgcn_mfma_f32_16x16x16f16(al, bl, acc0, 0, 0, 0);
        acc1 = __builtin_amdgcn_mfma_f32_16x16x16f16(ah, bh, acc1, 0, 0, 0);
    }
    float acc[4];
    #pragma unroll
    for (int i = 0; i < 4; ++i) acc[i] = acc0[i] + acc1[i];
    const int obase = ot + 4 * g;              // o = obase + i, p fixed

    if constexpr (EPI == 0) {                  // qkv: o<64 q, <128 k, else v
        const int dlo = 4 * (g & 1);
        if (ot < 64) {
            const float* qb = s ? b1 : b0;
            const float4 bv = *(const float4*)(qb + obase);
            const int h = (ot >> 3) + (g >> 1);
            half4f o = { (_Float16)((acc[0] + bv.x) * kScale), (_Float16)((acc[1] + bv.y) * kScale),
                         (_Float16)((acc[2] + bv.z) * kScale), (_Float16)((acc[3] + bv.w) * kScale) };
            *(half4f*)(o16a + (((size_t)combo * 8 + h) * kP + p) * 8 + dlo) = o;
        } else if (ot < 128) {
            const float* kb = s ? b3 : b2;
            const float4 bv = *(const float4*)(kb + obase - 64);
            const int h = ((ot - 64) >> 3) + (g >> 1);
            half4f o = { (_Float16)(acc[0] + bv.x), (_Float16)(acc[1] + bv.y),
                         (_Float16)(acc[2] + bv.z), (_Float16)(acc[3] + bv.w) };
            *(half4f*)(o16b + (((size_t)combo * 8 + h) * kP + p) * 8 + dlo) = o;
        } else {
            const float* kb = s ? b3 : b2;
            const float4 bv = *(const float4*)(kb + obase - 64);
            const int h = ((ot - 128) >> 3) + (g >> 1);
            const float* bvp = (const float*)&bv;
            #pragma unroll
            for (int i = 0; i < 4; ++i)
                o16c[(((size_t)combo * 8 + h) * 8 + dlo + i) * kP + p] = (_Float16)(acc[i] + bvp[i]);
        }
    } else if constexpr (EPI == 1) {           // proj -> c16 [combo][p][256]
        const float* pb = s ? b1 : b0;
        const float4 bv = *(const float4*)(pb + obase);
        half4f o = { (_Float16)(acc[0] + bv.x), (_Float16)(acc[1] + bv.y),
                     (_Float16)(acc[2] + bv.z), (_Float16)(acc[3] + bv.w) };
        *(half4f*)(o16a + ((size_t)combo * kP + p) * 256 + obase) = o;
    } else {                                   // gate: sigmoid + residual -> f32 out
        const float* gb = s ? b1 : b0;
        const float4 bv = *(const float4*)(gb + obase);
        const float* bvp = (const float*)&bv;
        const half4f cx = *(const half4f*)(B + ((size_t)combo * kP + p) * 512 + 256 + obase);
        const float* F = s ? f1 : f0;
        #pragma unroll
        for (int i = 0; i < 4; ++i) {
            const int o = obase + i;
            const float gt = 1.f / (1.f + __expf(-(acc[i] + bvp[i])));
            const float fb = F[((size_t)bb * kDim + o) * kP + p];
            outp[((size_t)combo * kDim + o) * kP + p] = fb + gt * (float)cx[i];
        }
    }
}

// ---------------- fused MFMA flash attention (both streams). grid (36, 16, 2).
__global__ __launch_bounds__(256) void attn_mfma(
    const _Float16* __restrict__ q16, const _Float16* __restrict__ k16,
    const _Float16* __restrict__ vt16, _Float16* __restrict__ a16)
{
    __shared__ _Float16 Ksm[256 * 24];   // 48B rows: halfs 0..7 = K[d], 8..15 = zeros
    __shared__ _Float16 Vsm[16 * 264];   // rows d (8 real + 8 zero), 264-half pitch
    const int st = blockIdx.z;
    const _Float16* Qg = q16  + (size_t)st * kInpStride;
    const _Float16* Kg = k16  + (size_t)(1 - st) * kInpStride;
    const _Float16* Vg = vt16 + (size_t)(1 - st) * kInpStride;
    const int bh = blockIdx.y;
    const int bb = bh >> 3, h = bh & 7;
    const int tid  = threadIdx.x;
    const int wv   = tid >> 6;
    const int lane = tid & 63;
    const int r16  = lane & 15;
    const int g    = lane >> 4;

    {
        const float4 z4 = make_float4(0.f, 0.f, 0.f, 0.f);
        *(float4*)(Ksm + tid * 24 + 8) = z4;
        for (int i = tid; i < 264; i += 256)
            *(float4*)(Vsm + 8 * 264 + i * 8) = z4;
    }

    const int qg = blockIdx.x * 64 + wv * 16 + r16;
    half4f qf = (half4f){0, 0, 0, 0};
    if (g < 2) qf = *(const half4f*)(Qg + ((size_t)bh * kP + qg) * 8 + g * 4);

    f32x4 of = (f32x4){0.f, 0.f, 0.f, 0.f};
    float rs = 0.f;

    for (int ch = 0; ch < 9; ++ch) {
        if (ch) __syncthreads();
        const int p0 = ch * 256;
        *(float4*)(Ksm + tid * 24) = *(const float4*)(Kg + ((size_t)bh * kP + p0 + tid) * 8);
        {
            const int d = tid >> 5, c8 = (tid & 31) * 8;
            *(float4*)(Vsm + d * 264 + c8) =
                *(const float4*)(Vg + ((size_t)(bh * 8 + d)) * kP + p0 + c8);
        }
        __syncthreads();
        #pragma unroll
        for (int kt = 0; kt < 16; ++kt) {
            const half4f kf = *(const half4f*)(Ksm + (kt * 16 + r16) * 24 + g * 4);
            f32x4 s = __builtin_amdgcn_mfma_f32_16x16x16f16(kf, qf, (f32x4){0.f,0.f,0.f,0.f}, 0, 0, 0);
            const float e0 = __expf(s[0]), e1 = __expf(s[1]);
            const float e2 = __expf(s[2]), e3 = __expf(s[3]);
            rs += (e0 + e1) + (e2 + e3);
            const half4f pf = { (_Float16)e0, (_Float16)e1, (_Float16)e2, (_Float16)e3 };
            const half4f vf = *(const half4f*)(Vsm + r16 * 264 + kt * 16 + g * 4);
            of = __builtin_amdgcn_mfma_f32_16x16x16f16(vf, pf, of, 0, 0, 0);
        }
    }
    rs += __shfl_xor(rs, 16, 64);
    rs += __shfl_xor(rs, 32, 64);
    const float inv = 1.f / rs;
    if (g < 2) {   // lane holds d = h*8 + 4g + i at position qg
        half4f o = { (_Float16)(of[0] * inv), (_Float16)(of[1] * inv),
                     (_Float16)(of[2] * inv), (_Float16)(of[3] * inv) };
        *(half4f*)(a16 + ((size_t)(st * 2 + bb) * kP + qg) * 64 + h * 8 + g * 4) = o;
    }
}

extern "C" void kernel_launch(void* const* d_in, const int* in_sizes, int n_in,
                              void* d_out, int out_size, void* d_ws, size_t ws_size,
                              hipStream_t stream)
{
    const float* f_rgb  = (const float*)d_in[0];
    const float* f_ir   = (const float*)d_in[1];
    const float* nr_w   = (const float*)d_in[2];
    const float* nr_b   = (const float*)d_in[3];
    const float* ni_w   = (const float*)d_in[4];
    const float* ni_b   = (const float*)d_in[5];
    const float* qr_w   = (const float*)d_in[6];
    const float* qr_b   = (const float*)d_in[7];
    const float* kvi_w  = (const float*)d_in[8];
    const float* kvi_b  = (const float*)d_in[9];
    const float* qi_w   = (const float*)d_in[10];
    const float* qi_b   = (const float*)d_in[11];
    const float* kvr_w  = (const float*)d_in[12];
    const float* kvr_b  = (const float*)d_in[13];
    const float* pr_w   = (const float*)d_in[14];
    const float* pr_b   = (const float*)d_in[15];
    const float* pr_lnw = (const float*)d_in[16];
    const float* pr_lnb = (const float*)d_in[17];
    const float* pi_w   = (const float*)d_in[18];
    const float* pi_b   = (const float*)d_in[19];
    const float* pi_lnw = (const float*)d_in[20];
    const float* pi_lnb = (const float*)d_in[21];
    const float* gr_w   = (const float*)d_in[22];
    const float* gr_b   = (const float*)d_in[23];
    const float* gi_w   = (const float*)d_in[24];
    const float* gi_b   = (const float*)d_in[25];

    _Float16* hb   = (_Float16*)d_ws;
    _Float16* Xq   = hb + oXq;
    _Float16* q16  = hb + oQ16;
    _Float16* k16  = hb + oK16;
    _Float16* vt16 = hb + oV16;
    _Float16* a16  = hb + oA16;
    _Float16* Xg   = hb;            // aliases [Xq|q16|k16|vt16|a16] (dead by then)
    _Float16* c16  = hb + oC16;
    _Float16* W16  = hb + oW16;
    _Float16* Aq   = W16;           // [2][192][256]
    _Float16* Ap   = W16 + 98304;   // [2][256][64]
    _Float16* Ag   = W16 + 131072;  // [2][256][512]

    float* outp = (float*)d_out;
    const dim3 blk(256);

    // 1) weights -> f16
    wcast<<<dim3(64, 8), blk, 0, stream>>>(qr_w, kvr_w, qi_w, kvi_w, pr_w, pi_w, gr_w, gi_w, W16);
    // 2) LN of both inputs -> Xq f16 pos-major
    ln_pre<<<dim3(288, 2), blk, 0, stream>>>(f_rgb, nr_w, nr_b, f_ir, ni_w, ni_b, Xq);
    // 3) qkv GEMM (M=192, K=256)
    gemm_f16<192, 256, 0><<<dim3(1728), blk, 0, stream>>>(
        Aq, Xq, qr_b, qi_b, kvr_b, kvi_b, q16, k16, vt16, nullptr, nullptr, nullptr);
    // 4) fused MFMA attention -> a16 pos-major
    attn_mfma<<<dim3(36, 16, 2), blk, 0, stream>>>(q16, k16, vt16, a16);
    // 5) proj GEMM (M=256, K=64) -> c16
    gemm_f16<256, 64, 1><<<dim3(2304), blk, 0, stream>>>(
        Ap, a16, pr_b, pi_b, nullptr, nullptr, c16, nullptr, nullptr, nullptr, nullptr, nullptr);
    // 6) post-LN + build gate input Xg = [f16(f) | f16(LN(c))]
    ln_post<<<dim3(288, 2), blk, 0, stream>>>(c16, pr_lnw, pr_lnb, pi_lnw, pi_lnb,
                                              f_rgb, f_ir, Xg);
    // 7) gate GEMM (M=256, K=512) + sigmoid + residual -> out
    gemm_f16<256, 512, 2><<<dim3(2304), blk, 0, stream>>>(
        Ag, Xg, gr_b, gi_b, nullptr, nullptr, nullptr, nullptr, nullptr, f_rgb, f_ir, outp);
}

// Round 10
// 117.320 us; speedup vs baseline: 2.7723x; 1.1144x over previous
//
#include <hip/hip_runtime.h>

static constexpr int kDim   = 256;
static constexpr int kInner = 64;
static constexpr int kNH    = 8;
static constexpr int kB     = 2;
static constexpr int kP     = 2304;   // 48*48
static constexpr float kScale = 0.35355339059327373f; // 8^-0.5
static constexpr float kEps   = 1e-6f;

typedef _Float16 half4f __attribute__((ext_vector_type(4)));
typedef _Float16 half8  __attribute__((ext_vector_type(8)));
typedef float    f32x4  __attribute__((ext_vector_type(4)));

// ws layout in halfs:
static constexpr size_t oXq  = 0;          // [4 combo][2304][256]      = 2359296
static constexpr size_t oQ16 = 2359296;    // [2 inp][16 bh][2304][8]   = 589824
static constexpr size_t oK16 = 2949120;    // same                      = 589824
static constexpr size_t oV16 = 3538944;    // [2 inp][16 bh][8][2304]   = 589824
static constexpr size_t oA16 = 4128768;    // [4 combo][2304][64]       = 589824
// Xg aliases [0 .. 4718592): [4 combo][2304][512]  (written after all above dead)
static constexpr size_t oC16 = 4718592;    // [4 combo][2304][256]      = 2359296
static constexpr size_t oW16 = 7077888;    // weights f16               = 393216
static constexpr size_t kInpStride = 294912; // q16/k16/vt16 per-inp stride (halfs)

// ---------------- weight f32 -> f16 cast (8 segments). grid (64, 8).
__global__ __launch_bounds__(256) void wcast(
    const float* __restrict__ qr_w, const float* __restrict__ kvr_w,
    const float* __restrict__ qi_w, const float* __restrict__ kvi_w,
    const float* __restrict__ pr_w, const float* __restrict__ pi_w,
    const float* __restrict__ gr_w, const float* __restrict__ gi_w,
    _Float16* __restrict__ w16)    // base at oW16
{
    const float* src; _Float16* dst; int n;
    _Float16* Aq = w16;             // [2][192][256]
    _Float16* Ap = w16 + 98304;     // [2][256][64]
    _Float16* Ag = w16 + 131072;    // [2][256][512]
    switch (blockIdx.y) {
        case 0: src = qr_w;  dst = Aq;          n = 16384;  break;
        case 1: src = kvr_w; dst = Aq + 16384;  n = 32768;  break;
        case 2: src = qi_w;  dst = Aq + 49152;  n = 16384;  break;
        case 3: src = kvi_w; dst = Aq + 65536;  n = 32768;  break;
        case 4: src = pr_w;  dst = Ap;          n = 16384;  break;
        case 5: src = pi_w;  dst = Ap + 16384;  n = 16384;  break;
        case 6: src = gr_w;  dst = Ag;          n = 131072; break;
        default:src = gi_w;  dst = Ag + 131072; n = 131072; break;
    }
    for (int i = blockIdx.x * 256 + threadIdx.x; i < n; i += 64 * 256)
        dst[i] = (_Float16)src[i];
}

// ---------------- pre-LN: f32 [c][p] -> f16 Xq [combo][p][256].
// XCD-affine flat grid (576): fid&7 -> (inp,bb,half); fid>>3 -> 16-pos chunk.
__global__ __launch_bounds__(256) void ln_pre(
    const float* __restrict__ x0, const float* __restrict__ w0,
    const float* __restrict__ b0, const float* __restrict__ x1,
    const float* __restrict__ w1, const float* __restrict__ b1,
    _Float16* __restrict__ Xq)
{
    __shared__ float sb[16][16];
    __shared__ float ssb[16][16];
    const int fid = blockIdx.x;
    const int xcd = fid & 7, q = fid >> 3;      // q 0..71
    const int inp = (xcd >> 2) & 1, bb = (xcd >> 1) & 1, half = xcd & 1;
    const float* x = inp ? x1 : x0;
    const float* w = inp ? w1 : w0;
    const float* b = inp ? b1 : b0;
    const int pos = threadIdx.x & 15;
    const int grp = threadIdx.x >> 4;
    const int p   = half * 1152 + q * 16 + pos;
    const size_t base = (size_t)bb * kDim * kP + p;
    const int c0 = grp * 16;

    float v[16];
    float s = 0.f, ss = 0.f;
    #pragma unroll
    for (int j = 0; j < 16; ++j) {
        v[j] = x[base + (size_t)(c0 + j) * kP];
        s += v[j]; ss += v[j] * v[j];
    }
    sb[grp][pos] = s; ssb[grp][pos] = ss;
    __syncthreads();
    float st = 0.f, sst = 0.f;
    #pragma unroll
    for (int g = 0; g < 16; ++g) { st += sb[g][pos]; sst += ssb[g][pos]; }
    const float mean = st * (1.f / kDim);
    const float rstd = rsqrtf(sst * (1.f / kDim) - mean * mean + kEps);
    half8 h0, h1;
    #pragma unroll
    for (int j = 0; j < 8; ++j) {
        h0[j] = (_Float16)((v[j]     - mean) * rstd * w[c0 + j]     + b[c0 + j]);
        h1[j] = (_Float16)((v[j + 8] - mean) * rstd * w[c0 + j + 8] + b[c0 + j + 8]);
    }
    _Float16* dst = Xq + ((size_t)(inp * 2 + bb) * kP + p) * 256 + c0;
    *(half8*)dst       = h0;
    *(half8*)(dst + 8) = h1;
}

// ---------------- post-LN: c16 -> LN -> Xg[..][256..512); raw f -> Xg[..][0..256).
// XCD-affine flat grid (576): fid&7 -> (s,bb,half) — SAME mapping as gate gemm.
__global__ __launch_bounds__(256) void ln_post(
    const _Float16* __restrict__ c16,
    const float* __restrict__ w0, const float* __restrict__ b0,
    const float* __restrict__ w1, const float* __restrict__ b1,
    const float* __restrict__ f0, const float* __restrict__ f1,
    _Float16* __restrict__ Xg)
{
    __shared__ float sb[16][16];
    __shared__ float ssb[16][16];
    const int fid = blockIdx.x;
    const int xcd = fid & 7, q = fid >> 3;      // q 0..71
    const int s = (xcd >> 2) & 1, bb = (xcd >> 1) & 1, half = xcd & 1;
    const float* w = s ? w1 : w0;
    const float* b = s ? b1 : b0;
    const float* F = s ? f1 : f0;
    const int pos = threadIdx.x & 15;
    const int grp = threadIdx.x >> 4;
    const int p   = half * 1152 + q * 16 + pos;
    const int c0  = grp * 16;
    const size_t combo = s * 2 + bb;

    const _Float16* cp = c16 + (combo * kP + p) * 256 + c0;
    const half8 g0 = *(const half8*)cp;
    const half8 g1 = *(const half8*)(cp + 8);
    float v[16];
    float sm = 0.f, ssq = 0.f;
    #pragma unroll
    for (int j = 0; j < 8; ++j) {
        v[j] = (float)g0[j]; v[j + 8] = (float)g1[j];
    }
    #pragma unroll
    for (int j = 0; j < 16; ++j) { sm += v[j]; ssq += v[j] * v[j]; }
    sb[grp][pos] = sm; ssb[grp][pos] = ssq;
    __syncthreads();
    float st = 0.f, sst = 0.f;
    #pragma unroll
    for (int g = 0; g < 16; ++g) { st += sb[g][pos]; sst += ssb[g][pos]; }
    const float mean = st * (1.f / kDim);
    const float rstd = rsqrtf(sst * (1.f / kDim) - mean * mean + kEps);

    _Float16* xrow = Xg + (combo * kP + p) * 512;
    half8 o0, o1;
    #pragma unroll
    for (int j = 0; j < 8; ++j) {
        o0[j] = (_Float16)((v[j]     - mean) * rstd * w[c0 + j]     + b[c0 + j]);
        o1[j] = (_Float16)((v[j + 8] - mean) * rstd * w[c0 + j + 8] + b[c0 + j + 8]);
    }
    *(half8*)(xrow + 256 + c0)     = o0;
    *(half8*)(xrow + 256 + c0 + 8) = o1;
    const size_t fbase = (size_t)bb * kDim * kP + p;
    half8 r0, r1;
    #pragma unroll
    for (int j = 0; j < 8; ++j) {
        r0[j] = (_Float16)F[fbase + (size_t)(c0 + j) * kP];
        r1[j] = (_Float16)F[fbase + (size_t)(c0 + j + 8) * kP];
    }
    *(half8*)(xrow + c0)     = r0;
    *(half8*)(xrow + c0 + 8) = r1;
}

// ---------------- f16 MFMA GEMM, 64o x 64p block tile, 4 acc-chains per wave.
// XCD-affine flat grid: fid&7 -> (s,bb,half); fid>>3 -> (o-tile64, p-tile64).
// EPI: 0 = qkv routing, 1 = proj (c16), 2 = gate (sigmoid+residual f32).
template <int M, int K, int EPI>
__global__ __launch_bounds__(256) void gemm_f16(
    const _Float16* __restrict__ A,     // [2][M][K] f16 weights
    const _Float16* __restrict__ B,     // [4][2304][K] f16 activations
    const float* __restrict__ b0, const float* __restrict__ b1,
    const float* __restrict__ b2, const float* __restrict__ b3,
    _Float16* __restrict__ o16a, _Float16* __restrict__ o16b, _Float16* __restrict__ o16c,
    const float* __restrict__ f0, const float* __restrict__ f1,
    float* __restrict__ outp)
{
    constexpr int MT64 = M / 64;
    const int fid = blockIdx.x;
    const int xcd = fid & 7, q = fid >> 3;
    const int s = (xcd >> 2) & 1, bb = (xcd >> 1) & 1, half = xcd & 1;
    const int ot64 = (q % MT64) * 64;
    const int pt   = q / MT64;                 // 0..17
    const int wv = threadIdx.x >> 6, lane = threadIdx.x & 63;
    const int r16 = lane & 15, g = lane >> 4;
    const int ot = ot64 + wv * 16;             // wave's 16-o tile
    const int p0 = half * 1152 + pt * 64;      // block's 64-p tile
    const int combo = s * 2 + bb;

    const _Float16* Ar = A + ((size_t)s * M + ot + r16) * K + 8 * g;
    const _Float16* Br = B + ((size_t)combo * kP + p0 + r16) * K + 8 * g;
    f32x4 acc0[4], acc1[4];
    #pragma unroll
    for (int ps = 0; ps < 4; ++ps) {
        acc0[ps] = (f32x4){0.f, 0.f, 0.f, 0.f};
        acc1[ps] = (f32x4){0.f, 0.f, 0.f, 0.f};
    }
    #pragma unroll 4
    for (int c0 = 0; c0 < K; c0 += 32) {
        const half8 a8 = *(const half8*)(Ar + c0);
        half8 b8[4];
        #pragma unroll
        for (int ps = 0; ps < 4; ++ps)
            b8[ps] = *(const half8*)(Br + (size_t)(16 * ps) * K + c0);
        const half4f al = {a8[0], a8[1], a8[2], a8[3]};
        const half4f ah = {a8[4], a8[5], a8[6], a8[7]};
        #pragma unroll
        for (int ps = 0; ps < 4; ++ps) {
            const half4f bl = {b8[ps][0], b8[ps][1], b8[ps][2], b8[ps][3]};
            const half4f bh = {b8[ps][4], b8[ps][5], b8[ps][6], b8[ps][7]};
            acc0[ps] = __builtin_amdgcn_mfma_f32_16x16x16f16(al, bl, acc0[ps], 0, 0, 0);
            acc1[ps] = __builtin_amdgcn_mfma_f32_16x16x16f16(ah, bh, acc1[ps], 0, 0, 0);
        }
    }
    const int obase = ot + 4 * g;              // o = obase + i

    #pragma unroll
    for (int ps = 0; ps < 4; ++ps) {
        float acc[4];
        #pragma unroll
        for (int i = 0; i < 4; ++i) acc[i] = acc0[ps][i] + acc1[ps][i];
        const int p = p0 + 16 * ps + r16;

        if constexpr (EPI == 0) {              // qkv: ot64 0 = q, 64 = k, 128 = v
            const int dlo = 4 * (g & 1);
            if (ot < 64) {
                const float* qb = s ? b1 : b0;
                const float4 bv = *(const float4*)(qb + obase);
                const int h = (ot >> 3) + (g >> 1);
                half4f o = { (_Float16)((acc[0] + bv.x) * kScale), (_Float16)((acc[1] + bv.y) * kScale),
                             (_Float16)((acc[2] + bv.z) * kScale), (_Float16)((acc[3] + bv.w) * kScale) };
                *(half4f*)(o16a + (((size_t)combo * 8 + h) * kP + p) * 8 + dlo) = o;
            } else if (ot < 128) {
                const float* kb = s ? b3 : b2;
                const float4 bv = *(const float4*)(kb + obase - 64);
                const int h = ((ot - 64) >> 3) + (g >> 1);
                half4f o = { (_Float16)(acc[0] + bv.x), (_Float16)(acc[1] + bv.y),
                             (_Float16)(acc[2] + bv.z), (_Float16)(acc[3] + bv.w) };
                *(half4f*)(o16b + (((size_t)combo * 8 + h) * kP + p) * 8 + dlo) = o;
            } else {
                const float* kb = s ? b3 : b2;
                const float4 bv = *(const float4*)(kb + obase - 64);
                const int h = ((ot - 128) >> 3) + (g >> 1);
                const float* bvp = (const float*)&bv;
                #pragma unroll
                for (int i = 0; i < 4; ++i)
                    o16c[(((size_t)combo * 8 + h) * 8 + dlo + i) * kP + p] = (_Float16)(acc[i] + bvp[i]);
            }
        } else if constexpr (EPI == 1) {       // proj -> c16 [combo][p][256]
            const float* pb = s ? b1 : b0;
            const float4 bv = *(const float4*)(pb + obase);
            half4f o = { (_Float16)(acc[0] + bv.x), (_Float16)(acc[1] + bv.y),
                         (_Float16)(acc[2] + bv.z), (_Float16)(acc[3] + bv.w) };
            *(half4f*)(o16a + ((size_t)combo * kP + p) * 256 + obase) = o;
        } else {                               // gate: sigmoid + residual -> f32 out
            const float* gb = s ? b1 : b0;
            const float4 bv = *(const float4*)(gb + obase);
            const float* bvp = (const float*)&bv;
            const half4f cx = *(const half4f*)(B + ((size_t)combo * kP + p) * 512 + 256 + obase);
            const float* F = s ? f1 : f0;
            #pragma unroll
            for (int i = 0; i < 4; ++i) {
                const int o = obase + i;
                const float gt = 1.f / (1.f + __expf(-(acc[i] + bvp[i])));
                const float fb = F[((size_t)bb * kDim + o) * kP + p];
                outp[((size_t)combo * kDim + o) * kP + p] = fb + gt * (float)cx[i];
            }
        }
    }
}

// ---------------- fused MFMA flash attention (both streams). grid (36, 16, 2).
__global__ __launch_bounds__(256) void attn_mfma(
    const _Float16* __restrict__ q16, const _Float16* __restrict__ k16,
    const _Float16* __restrict__ vt16, _Float16* __restrict__ a16)
{
    __shared__ _Float16 Ksm[256 * 24];   // 48B rows: halfs 0..7 = K[d], 8..15 = zeros
    __shared__ _Float16 Vsm[16 * 264];   // rows d (8 real + 8 zero), 264-half pitch
    const int st = blockIdx.z;
    const _Float16* Qg = q16  + (size_t)st * kInpStride;
    const _Float16* Kg = k16  + (size_t)(1 - st) * kInpStride;
    const _Float16* Vg = vt16 + (size_t)(1 - st) * kInpStride;
    const int bh = blockIdx.y;
    const int bb = bh >> 3, h = bh & 7;
    const int tid  = threadIdx.x;
    const int wv   = tid >> 6;
    const int lane = tid & 63;
    const int r16  = lane & 15;
    const int g    = lane >> 4;

    {
        const float4 z4 = make_float4(0.f, 0.f, 0.f, 0.f);
        *(float4*)(Ksm + tid * 24 + 8) = z4;
        for (int i = tid; i < 264; i += 256)
            *(float4*)(Vsm + 8 * 264 + i * 8) = z4;
    }

    const int qg = blockIdx.x * 64 + wv * 16 + r16;
    half4f qf = (half4f){0, 0, 0, 0};
    if (g < 2) qf = *(const half4f*)(Qg + ((size_t)bh * kP + qg) * 8 + g * 4);

    f32x4 of = (f32x4){0.f, 0.f, 0.f, 0.f};
    float rs = 0.f;

    for (int ch = 0; ch < 9; ++ch) {
        if (ch) __syncthreads();
        const int p0 = ch * 256;
        *(float4*)(Ksm + tid * 24) = *(const float4*)(Kg + ((size_t)bh * kP + p0 + tid) * 8);
        {
            const int d = tid >> 5, c8 = (tid & 31) * 8;
            *(float4*)(Vsm + d * 264 + c8) =
                *(const float4*)(Vg + ((size_t)(bh * 8 + d)) * kP + p0 + c8);
        }
        __syncthreads();
        #pragma unroll
        for (int kt = 0; kt < 16; ++kt) {
            const half4f kf = *(const half4f*)(Ksm + (kt * 16 + r16) * 24 + g * 4);
            f32x4 s = __builtin_amdgcn_mfma_f32_16x16x16f16(kf, qf, (f32x4){0.f,0.f,0.f,0.f}, 0, 0, 0);
            const float e0 = __expf(s[0]), e1 = __expf(s[1]);
            const float e2 = __expf(s[2]), e3 = __expf(s[3]);
            rs += (e0 + e1) + (e2 + e3);
            const half4f pf = { (_Float16)e0, (_Float16)e1, (_Float16)e2, (_Float16)e3 };
            const half4f vf = *(const half4f*)(Vsm + r16 * 264 + kt * 16 + g * 4);
            of = __builtin_amdgcn_mfma_f32_16x16x16f16(vf, pf, of, 0, 0, 0);
        }
    }
    rs += __shfl_xor(rs, 16, 64);
    rs += __shfl_xor(rs, 32, 64);
    const float inv = 1.f / rs;
    if (g < 2) {   // lane holds d = h*8 + 4g + i at position qg
        half4f o = { (_Float16)(of[0] * inv), (_Float16)(of[1] * inv),
                     (_Float16)(of[2] * inv), (_Float16)(of[3] * inv) };
        *(half4f*)(a16 + ((size_t)(st * 2 + bb) * kP + qg) * 64 + h * 8 + g * 4) = o;
    }
}

extern "C" void kernel_launch(void* const* d_in, const int* in_sizes, int n_in,
                              void* d_out, int out_size, void* d_ws, size_t ws_size,
                              hipStream_t stream)
{
    const float* f_rgb  = (const float*)d_in[0];
    const float* f_ir   = (const float*)d_in[1];
    const float* nr_w   = (const float*)d_in[2];
    const float* nr_b   = (const float*)d_in[3];
    const float* ni_w   = (const float*)d_in[4];
    const float* ni_b   = (const float*)d_in[5];
    const float* qr_w   = (const float*)d_in[6];
    const float* qr_b   = (const float*)d_in[7];
    const float* kvi_w  = (const float*)d_in[8];
    const float* kvi_b  = (const float*)d_in[9];
    const float* qi_w   = (const float*)d_in[10];
    const float* qi_b   = (const float*)d_in[11];
    const float* kvr_w  = (const float*)d_in[12];
    const float* kvr_b  = (const float*)d_in[13];
    const float* pr_w   = (const float*)d_in[14];
    const float* pr_b   = (const float*)d_in[15];
    const float* pr_lnw = (const float*)d_in[16];
    const float* pr_lnb = (const float*)d_in[17];
    const float* pi_w   = (const float*)d_in[18];
    const float* pi_b   = (const float*)d_in[19];
    const float* pi_lnw = (const float*)d_in[20];
    const float* pi_lnb = (const float*)d_in[21];
    const float* gr_w   = (const float*)d_in[22];
    const float* gr_b   = (const float*)d_in[23];
    const float* gi_w   = (const float*)d_in[24];
    const float* gi_b   = (const float*)d_in[25];

    _Float16* hb   = (_Float16*)d_ws;
    _Float16* Xq   = hb + oXq;
    _Float16* q16  = hb + oQ16;
    _Float16* k16  = hb + oK16;
    _Float16* vt16 = hb + oV16;
    _Float16* a16  = hb + oA16;
    _Float16* Xg   = hb;            // aliases [Xq|q16|k16|vt16|a16] (dead by then)
    _Float16* c16  = hb + oC16;
    _Float16* W16  = hb + oW16;
    _Float16* Aq   = W16;           // [2][192][256]
    _Float16* Ap   = W16 + 98304;   // [2][256][64]
    _Float16* Ag   = W16 + 131072;  // [2][256][512]

    float* outp = (float*)d_out;
    const dim3 blk(256);

    // 1) weights -> f16
    wcast<<<dim3(64, 8), blk, 0, stream>>>(qr_w, kvr_w, qi_w, kvi_w, pr_w, pi_w, gr_w, gi_w, W16);
    // 2) LN of both inputs -> Xq f16 pos-major (XCD-affine)
    ln_pre<<<dim3(576), blk, 0, stream>>>(f_rgb, nr_w, nr_b, f_ir, ni_w, ni_b, Xq);
    // 3) qkv GEMM (M=192, K=256): 8 xcd-combos x 3 o-tiles x 18 p-tiles
    gemm_f16<192, 256, 0><<<dim3(432), blk, 0, stream>>>(
        Aq, Xq, qr_b, qi_b, kvr_b, kvi_b, q16, k16, vt16, nullptr, nullptr, nullptr);
    // 4) fused MFMA attention -> a16 pos-major
    attn_mfma<<<dim3(36, 16, 2), blk, 0, stream>>>(q16, k16, vt16, a16);
    // 5) proj GEMM (M=256, K=64) -> c16
    gemm_f16<256, 64, 1><<<dim3(576), blk, 0, stream>>>(
        Ap, a16, pr_b, pi_b, nullptr, nullptr, c16, nullptr, nullptr, nullptr, nullptr, nullptr);
    // 6) post-LN + build gate input Xg = [f16(f) | f16(LN(c))] (XCD-affine)
    ln_post<<<dim3(576), blk, 0, stream>>>(c16, pr_lnw, pr_lnb, pi_lnw, pi_lnb,
                                           f_rgb, f_ir, Xg);
    // 7) gate GEMM (M=256, K=512) + sigmoid + residual -> out
    gemm_f16<256, 512, 2><<<dim3(576), blk, 0, stream>>>(
        Ag, Xg, gr_b, gi_b, nullptr, nullptr, nullptr, nullptr, nullptr, f_rgb, f_ir, outp);
}

// Round 12
// 111.747 us; speedup vs baseline: 2.9106x; 1.0499x over previous
//
#include <hip/hip_runtime.h>

static constexpr int kDim   = 256;
static constexpr int kInner = 64;
static constexpr int kNH    = 8;
static constexpr int kB     = 2;
static constexpr int kP     = 2304;   // 48*48
static constexpr float kScale = 0.35355339059327373f; // 8^-0.5
static constexpr float kEps   = 1e-6f;

typedef __fp16   fp16x2 __attribute__((ext_vector_type(2)));
typedef _Float16 half4f __attribute__((ext_vector_type(4)));
typedef _Float16 half8  __attribute__((ext_vector_type(8)));
typedef float    f32x4  __attribute__((ext_vector_type(4)));

// ws layout in halfs:
static constexpr size_t oXq  = 0;          // [4 combo][2304][256]      = 2359296
static constexpr size_t oQ16 = 2359296;    // [2 inp][16 bh][2304][8]   = 589824
static constexpr size_t oK16 = 2949120;    // same                      = 589824
static constexpr size_t oV16 = 3538944;    // [2 inp][16 bh][8][2304]   = 589824
static constexpr size_t oA16 = 4128768;    // [4 combo][2304][64]       = 589824
// Xg aliases [0 .. 4718592): [4 combo][2304][512]  (written after all above dead)
static constexpr size_t oC16 = 4718592;    // [4 combo][2304][256]      = 2359296
static constexpr size_t oW16 = 7077888;    // weights f16               = 393216
static constexpr size_t kInpStride = 294912; // q16/k16/vt16 per-inp stride (halfs)

// ---------------- prep: blocks <576 do pre-LN (XCD-affine); blocks >=576 cast weights.
__global__ __launch_bounds__(256) void prep(
    const float* __restrict__ x0, const float* __restrict__ w0,
    const float* __restrict__ b0, const float* __restrict__ x1,
    const float* __restrict__ w1, const float* __restrict__ b1,
    _Float16* __restrict__ Xq,
    const float* __restrict__ qr_w, const float* __restrict__ kvr_w,
    const float* __restrict__ qi_w, const float* __restrict__ kvi_w,
    const float* __restrict__ pr_w, const float* __restrict__ pi_w,
    const float* __restrict__ gr_w, const float* __restrict__ gi_w,
    _Float16* __restrict__ w16)
{
    if (blockIdx.x >= 576) {               // weight cast
        const int flat = blockIdx.x - 576;
        const int y = flat >> 6, x = flat & 63;
        const float* src; _Float16* dst; int n;
        _Float16* Aq = w16;             // [2][192][256]
        _Float16* Ap = w16 + 98304;     // [2][256][64]
        _Float16* Ag = w16 + 131072;    // [2][256][512]
        switch (y) {
            case 0: src = qr_w;  dst = Aq;          n = 16384;  break;
            case 1: src = kvr_w; dst = Aq + 16384;  n = 32768;  break;
            case 2: src = qi_w;  dst = Aq + 49152;  n = 16384;  break;
            case 3: src = kvi_w; dst = Aq + 65536;  n = 32768;  break;
            case 4: src = pr_w;  dst = Ap;          n = 16384;  break;
            case 5: src = pi_w;  dst = Ap + 16384;  n = 16384;  break;
            case 6: src = gr_w;  dst = Ag;          n = 131072; break;
            default:src = gi_w;  dst = Ag + 131072; n = 131072; break;
        }
        for (int i = x * 256 + threadIdx.x; i < n; i += 64 * 256)
            dst[i] = (_Float16)src[i];
        return;
    }
    // pre-LN
    __shared__ float sb[16][16];
    __shared__ float ssb[16][16];
    const int fid = blockIdx.x;
    const int xcd = fid & 7, q = fid >> 3;      // q 0..71
    const int inp = (xcd >> 2) & 1, bb = (xcd >> 1) & 1, half = xcd & 1;
    const float* x = inp ? x1 : x0;
    const float* w = inp ? w1 : w0;
    const float* b = inp ? b1 : b0;
    const int pos = threadIdx.x & 15;
    const int grp = threadIdx.x >> 4;
    const int p   = half * 1152 + q * 16 + pos;
    const size_t base = (size_t)bb * kDim * kP + p;
    const int c0 = grp * 16;

    float v[16];
    float s = 0.f, ss = 0.f;
    #pragma unroll
    for (int j = 0; j < 16; ++j) {
        v[j] = x[base + (size_t)(c0 + j) * kP];
        s += v[j]; ss += v[j] * v[j];
    }
    sb[grp][pos] = s; ssb[grp][pos] = ss;
    __syncthreads();
    float st = 0.f, sst = 0.f;
    #pragma unroll
    for (int g = 0; g < 16; ++g) { st += sb[g][pos]; sst += ssb[g][pos]; }
    const float mean = st * (1.f / kDim);
    const float rstd = rsqrtf(sst * (1.f / kDim) - mean * mean + kEps);
    half8 h0, h1;
    #pragma unroll
    for (int j = 0; j < 8; ++j) {
        h0[j] = (_Float16)((v[j]     - mean) * rstd * w[c0 + j]     + b[c0 + j]);
        h1[j] = (_Float16)((v[j + 8] - mean) * rstd * w[c0 + j + 8] + b[c0 + j + 8]);
    }
    _Float16* dst = Xq + ((size_t)(inp * 2 + bb) * kP + p) * 256 + c0;
    *(half8*)dst       = h0;
    *(half8*)(dst + 8) = h1;
}

// ---------------- post-LN: c16 -> LN -> Xg[..][256..512); raw f -> Xg[..][0..256).
// XCD-affine flat grid (576): fid&7 -> (s,bb,half) — SAME mapping as gate gemm.
__global__ __launch_bounds__(256) void ln_post(
    const _Float16* __restrict__ c16,
    const float* __restrict__ w0, const float* __restrict__ b0,
    const float* __restrict__ w1, const float* __restrict__ b1,
    const float* __restrict__ f0, const float* __restrict__ f1,
    _Float16* __restrict__ Xg)
{
    __shared__ float sb[16][16];
    __shared__ float ssb[16][16];
    const int fid = blockIdx.x;
    const int xcd = fid & 7, q = fid >> 3;      // q 0..71
    const int s = (xcd >> 2) & 1, bb = (xcd >> 1) & 1, half = xcd & 1;
    const float* w = s ? w1 : w0;
    const float* b = s ? b1 : b0;
    const float* F = s ? f1 : f0;
    const int pos = threadIdx.x & 15;
    const int grp = threadIdx.x >> 4;
    const int p   = half * 1152 + q * 16 + pos;
    const int c0  = grp * 16;
    const size_t combo = s * 2 + bb;

    const _Float16* cp = c16 + (combo * kP + p) * 256 + c0;
    const half8 g0 = *(const half8*)cp;
    const half8 g1 = *(const half8*)(cp + 8);
    float v[16];
    float sm = 0.f, ssq = 0.f;
    #pragma unroll
    for (int j = 0; j < 8; ++j) {
        v[j] = (float)g0[j]; v[j + 8] = (float)g1[j];
    }
    #pragma unroll
    for (int j = 0; j < 16; ++j) { sm += v[j]; ssq += v[j] * v[j]; }
    sb[grp][pos] = sm; ssb[grp][pos] = ssq;
    __syncthreads();
    float st = 0.f, sst = 0.f;
    #pragma unroll
    for (int g = 0; g < 16; ++g) { st += sb[g][pos]; sst += ssb[g][pos]; }
    const float mean = st * (1.f / kDim);
    const float rstd = rsqrtf(sst * (1.f / kDim) - mean * mean + kEps);

    _Float16* xrow = Xg + (combo * kP + p) * 512;
    half8 o0, o1;
    #pragma unroll
    for (int j = 0; j < 8; ++j) {
        o0[j] = (_Float16)((v[j]     - mean) * rstd * w[c0 + j]     + b[c0 + j]);
        o1[j] = (_Float16)((v[j + 8] - mean) * rstd * w[c0 + j + 8] + b[c0 + j + 8]);
    }
    *(half8*)(xrow + 256 + c0)     = o0;
    *(half8*)(xrow + 256 + c0 + 8) = o1;
    const size_t fbase = (size_t)bb * kDim * kP + p;
    half8 r0, r1;
    #pragma unroll
    for (int j = 0; j < 8; ++j) {
        r0[j] = (_Float16)F[fbase + (size_t)(c0 + j) * kP];
        r1[j] = (_Float16)F[fbase + (size_t)(c0 + j + 8) * kP];
    }
    *(half8*)(xrow + c0)     = r0;
    *(half8*)(xrow + c0 + 8) = r1;
}

// ---------------- f16 MFMA GEMM, 64o x 64p block tile, 4 acc-chains per wave.
// XCD-affine flat grid: fid&7 -> (s,bb,half); fid>>3 -> (o-tile64, p-tile64).
// EPI: 0 = qkv routing, 1 = proj (c16), 2 = gate (sigmoid+residual f32).
template <int M, int K, int EPI>
__global__ __launch_bounds__(256) void gemm_f16(
    const _Float16* __restrict__ A,     // [2][M][K] f16 weights
    const _Float16* __restrict__ B,     // [4][2304][K] f16 activations
    const float* __restrict__ b0, const float* __restrict__ b1,
    const float* __restrict__ b2, const float* __restrict__ b3,
    _Float16* __restrict__ o16a, _Float16* __restrict__ o16b, _Float16* __restrict__ o16c,
    const float* __restrict__ f0, const float* __restrict__ f1,
    float* __restrict__ outp)
{
    constexpr int MT64 = M / 64;
    const int fid = blockIdx.x;
    const int xcd = fid & 7, q = fid >> 3;
    const int s = (xcd >> 2) & 1, bb = (xcd >> 1) & 1, half = xcd & 1;
    const int ot64 = (q % MT64) * 64;
    const int pt   = q / MT64;                 // 0..17
    const int wv = threadIdx.x >> 6, lane = threadIdx.x & 63;
    const int r16 = lane & 15, g = lane >> 4;
    const int ot = ot64 + wv * 16;             // wave's 16-o tile
    const int p0 = half * 1152 + pt * 64;      // block's 64-p tile
    const int combo = s * 2 + bb;

    const _Float16* Ar = A + ((size_t)s * M + ot + r16) * K + 8 * g;
    const _Float16* Br = B + ((size_t)combo * kP + p0 + r16) * K + 8 * g;
    f32x4 acc0[4], acc1[4];
    #pragma unroll
    for (int ps = 0; ps < 4; ++ps) {
        acc0[ps] = (f32x4){0.f, 0.f, 0.f, 0.f};
        acc1[ps] = (f32x4){0.f, 0.f, 0.f, 0.f};
    }
    #pragma unroll 4
    for (int c0 = 0; c0 < K; c0 += 32) {
        const half8 a8 = *(const half8*)(Ar + c0);
        half8 b8[4];
        #pragma unroll
        for (int ps = 0; ps < 4; ++ps)
            b8[ps] = *(const half8*)(Br + (size_t)(16 * ps) * K + c0);
        const half4f al = {a8[0], a8[1], a8[2], a8[3]};
        const half4f ah = {a8[4], a8[5], a8[6], a8[7]};
        #pragma unroll
        for (int ps = 0; ps < 4; ++ps) {
            const half4f bl = {b8[ps][0], b8[ps][1], b8[ps][2], b8[ps][3]};
            const half4f bh = {b8[ps][4], b8[ps][5], b8[ps][6], b8[ps][7]};
            acc0[ps] = __builtin_amdgcn_mfma_f32_16x16x16f16(al, bl, acc0[ps], 0, 0, 0);
            acc1[ps] = __builtin_amdgcn_mfma_f32_16x16x16f16(ah, bh, acc1[ps], 0, 0, 0);
        }
    }
    const int obase = ot + 4 * g;              // o = obase + i

    #pragma unroll
    for (int ps = 0; ps < 4; ++ps) {
        float acc[4];
        #pragma unroll
        for (int i = 0; i < 4; ++i) acc[i] = acc0[ps][i] + acc1[ps][i];
        const int p = p0 + 16 * ps + r16;

        if constexpr (EPI == 0) {              // qkv: ot64 0 = q, 64 = k, 128 = v
            const int dlo = 4 * (g & 1);
            if (ot < 64) {
                const float* qb = s ? b1 : b0;
                const float4 bv = *(const float4*)(qb + obase);
                const int h = (ot >> 3) + (g >> 1);
                half4f o = { (_Float16)((acc[0] + bv.x) * kScale), (_Float16)((acc[1] + bv.y) * kScale),
                             (_Float16)((acc[2] + bv.z) * kScale), (_Float16)((acc[3] + bv.w) * kScale) };
                *(half4f*)(o16a + (((size_t)combo * 8 + h) * kP + p) * 8 + dlo) = o;
            } else if (ot < 128) {
                const float* kb = s ? b3 : b2;
                const float4 bv = *(const float4*)(kb + obase - 64);
                const int h = ((ot - 64) >> 3) + (g >> 1);
                half4f o = { (_Float16)(acc[0] + bv.x), (_Float16)(acc[1] + bv.y),
                             (_Float16)(acc[2] + bv.z), (_Float16)(acc[3] + bv.w) };
                *(half4f*)(o16b + (((size_t)combo * 8 + h) * kP + p) * 8 + dlo) = o;
            } else {
                const float* kb = s ? b3 : b2;
                const float4 bv = *(const float4*)(kb + obase - 64);
                const int h = ((ot - 128) >> 3) + (g >> 1);
                const float* bvp = (const float*)&bv;
                #pragma unroll
                for (int i = 0; i < 4; ++i)
                    o16c[(((size_t)combo * 8 + h) * 8 + dlo + i) * kP + p] = (_Float16)(acc[i] + bvp[i]);
            }
        } else if constexpr (EPI == 1) {       // proj -> c16 [combo][p][256]
            const float* pb = s ? b1 : b0;
            const float4 bv = *(const float4*)(pb + obase);
            half4f o = { (_Float16)(acc[0] + bv.x), (_Float16)(acc[1] + bv.y),
                         (_Float16)(acc[2] + bv.z), (_Float16)(acc[3] + bv.w) };
            *(half4f*)(o16a + ((size_t)combo * kP + p) * 256 + obase) = o;
        } else {                               // gate: sigmoid + residual -> f32 out
            const float* gb = s ? b1 : b0;
            const float4 bv = *(const float4*)(gb + obase);
            const float* bvp = (const float*)&bv;
            const half4f cx = *(const half4f*)(B + ((size_t)combo * kP + p) * 512 + 256 + obase);
            const float* F = s ? f1 : f0;
            #pragma unroll
            for (int i = 0; i < 4; ++i) {
                const int o = obase + i;
                const float gt = 1.f / (1.f + __expf(-(acc[i] + bvp[i])));
                const float fb = F[((size_t)bb * kDim + o) * kP + p];
                outp[((size_t)combo * kDim + o) * kP + p] = fb + gt * (float)cx[i];
            }
        }
    }
}

// ---------------- fused MFMA flash attention, frag-order LDS + ones-row rowsum.
// grid (36, 16, 2): x = q-tile of 64, y = bh, z = stream. block 256 = 4 waves x 16 q.
__global__ __launch_bounds__(256) void attn_mfma(
    const _Float16* __restrict__ q16, const _Float16* __restrict__ k16,
    const _Float16* __restrict__ vt16, _Float16* __restrict__ a16)
{
    __shared__ _Float16 Ksm[16 * 64 * 4];   // [kt][lane] 8B frags, 8KB
    __shared__ _Float16 Vsm[16 * 64 * 4];   // [kt][lane] 8B frags, 8KB
    const int st = blockIdx.z;
    const _Float16* Qg = q16  + (size_t)st * kInpStride;
    const _Float16* Kg = k16  + (size_t)(1 - st) * kInpStride;
    const _Float16* Vg = vt16 + (size_t)(1 - st) * kInpStride;
    const int bh = blockIdx.y;
    const int bb = bh >> 3, h = bh & 7;
    const int tid  = threadIdx.x;
    const int wv   = tid >> 6;
    const int lane = tid & 63;
    const int r16  = lane & 15;
    const int g    = lane >> 4;

    // prefill static pad slots: K lanes 32..63 = 0; V rows r16>=8 (ones at r16==8)
    #pragma unroll
    for (int j = 0; j < 2; ++j) {
        const int s = tid + 256 * j;            // 0..511
        const int kt = s >> 5, m = s & 31;
        *(half4f*)(Ksm + (kt * 64 + 32 + m) * 4) = (half4f){0, 0, 0, 0};
        const int rv = 8 + (m & 7), gv = m >> 3;
        const half4f vv = (rv == 8)
            ? (half4f){(_Float16)1.f, (_Float16)1.f, (_Float16)1.f, (_Float16)1.f}
            : (half4f){0, 0, 0, 0};
        *(half4f*)(Vsm + (kt * 64 + gv * 16 + rv) * 4) = vv;
    }

    const int qg = blockIdx.x * 64 + wv * 16 + r16;
    half4f qf = (half4f){0, 0, 0, 0};
    if (g < 2) qf = *(const half4f*)(Qg + ((size_t)bh * kP + qg) * 8 + g * 4);

    f32x4 of = (f32x4){0.f, 0.f, 0.f, 0.f};

    for (int ch = 0; ch < 9; ++ch) {
        if (ch) __syncthreads();                // prev reads done before re-stage
        const int p0 = ch * 256;
        {   // K stage: thread = key; frags (g'=0,1) -> slots l=r16, l=16+r16
            const half8 k8 = *(const half8*)(Kg + ((size_t)bh * kP + p0 + tid) * 8);
            _Float16* base = Ksm + ((tid >> 4) * 64 + (tid & 15)) * 4;
            *(half4f*)base        = (half4f){k8[0], k8[1], k8[2], k8[3]};
            *(half4f*)(base + 64) = (half4f){k8[4], k8[5], k8[6], k8[7]};
        }
        {   // V stage: thread covers row d, cols c8..c8+7 -> slots (kt, gv, d), (kt, gv+1, d)
            const int d = tid >> 5, c8 = (tid & 31) * 8;
            const half8 v8 = *(const half8*)(Vg + (size_t)(bh * 8 + d) * kP + p0 + c8);
            const int kt = c8 >> 4, gv = (c8 & 15) >> 2;
            _Float16* base = Vsm + (kt * 64 + gv * 16 + d) * 4;
            *(half4f*)base        = (half4f){v8[0], v8[1], v8[2], v8[3]};
            *(half4f*)(base + 64) = (half4f){v8[4], v8[5], v8[6], v8[7]};
        }
        __syncthreads();
        #pragma unroll
        for (int kt = 0; kt < 16; ++kt) {
            const half4f kf = *(const half4f*)(Ksm + kt * 256 + lane * 4);
            f32x4 sv = __builtin_amdgcn_mfma_f32_16x16x16f16(kf, qf, (f32x4){0.f,0.f,0.f,0.f}, 0, 0, 0);
            const float e0 = __expf(sv[0]), e1 = __expf(sv[1]);
            const float e2 = __expf(sv[2]), e3 = __expf(sv[3]);
            const fp16x2 lo = __builtin_amdgcn_cvt_pkrtz(e0, e1);
            const fp16x2 hi = __builtin_amdgcn_cvt_pkrtz(e2, e3);
            const half4f pf = { (_Float16)lo[0], (_Float16)lo[1],
                                (_Float16)hi[0], (_Float16)hi[1] };
            const half4f vf = *(const half4f*)(Vsm + kt * 256 + lane * 4);
            of = __builtin_amdgcn_mfma_f32_16x16x16f16(vf, pf, of, 0, 0, 0);
        }
    }
    // rowsum lives in PV output row 8 = lane (g=2, r16), reg 0
    const float rsv = __shfl(of[0], 32 + r16, 64);
    const float inv = 1.f / rsv;
    if (g < 2) {   // lane holds d = h*8 + 4g + i at position qg
        half4f o = { (_Float16)(of[0] * inv), (_Float16)(of[1] * inv),
                     (_Float16)(of[2] * inv), (_Float16)(of[3] * inv) };
        *(half4f*)(a16 + ((size_t)(st * 2 + bb) * kP + qg) * 64 + h * 8 + g * 4) = o;
    }
}

extern "C" void kernel_launch(void* const* d_in, const int* in_sizes, int n_in,
                              void* d_out, int out_size, void* d_ws, size_t ws_size,
                              hipStream_t stream)
{
    const float* f_rgb  = (const float*)d_in[0];
    const float* f_ir   = (const float*)d_in[1];
    const float* nr_w   = (const float*)d_in[2];
    const float* nr_b   = (const float*)d_in[3];
    const float* ni_w   = (const float*)d_in[4];
    const float* ni_b   = (const float*)d_in[5];
    const float* qr_w   = (const float*)d_in[6];
    const float* qr_b   = (const float*)d_in[7];
    const float* kvi_w  = (const float*)d_in[8];
    const float* kvi_b  = (const float*)d_in[9];
    const float* qi_w   = (const float*)d_in[10];
    const float* qi_b   = (const float*)d_in[11];
    const float* kvr_w  = (const float*)d_in[12];
    const float* kvr_b  = (const float*)d_in[13];
    const float* pr_w   = (const float*)d_in[14];
    const float* pr_b   = (const float*)d_in[15];
    const float* pr_lnw = (const float*)d_in[16];
    const float* pr_lnb = (const float*)d_in[17];
    const float* pi_w   = (const float*)d_in[18];
    const float* pi_b   = (const float*)d_in[19];
    const float* pi_lnw = (const float*)d_in[20];
    const float* pi_lnb = (const float*)d_in[21];
    const float* gr_w   = (const float*)d_in[22];
    const float* gr_b   = (const float*)d_in[23];
    const float* gi_w   = (const float*)d_in[24];
    const float* gi_b   = (const float*)d_in[25];

    _Float16* hb   = (_Float16*)d_ws;
    _Float16* Xq   = hb + oXq;
    _Float16* q16  = hb + oQ16;
    _Float16* k16  = hb + oK16;
    _Float16* vt16 = hb + oV16;
    _Float16* a16  = hb + oA16;
    _Float16* Xg   = hb;            // aliases [Xq|q16|k16|vt16|a16] (dead by then)
    _Float16* c16  = hb + oC16;
    _Float16* W16  = hb + oW16;
    _Float16* Aq   = W16;           // [2][192][256]
    _Float16* Ap   = W16 + 98304;   // [2][256][64]
    _Float16* Ag   = W16 + 131072;  // [2][256][512]

    float* outp = (float*)d_out;
    const dim3 blk(256);

    // 1) pre-LN (XCD-affine) + weight cast in one launch
    prep<<<dim3(1088), blk, 0, stream>>>(f_rgb, nr_w, nr_b, f_ir, ni_w, ni_b, Xq,
                                         qr_w, kvr_w, qi_w, kvi_w, pr_w, pi_w, gr_w, gi_w, W16);
    // 2) qkv GEMM (M=192, K=256)
    gemm_f16<192, 256, 0><<<dim3(432), blk, 0, stream>>>(
        Aq, Xq, qr_b, qi_b, kvr_b, kvi_b, q16, k16, vt16, nullptr, nullptr, nullptr);
    // 3) fused MFMA attention -> a16 pos-major
    attn_mfma<<<dim3(36, 16, 2), blk, 0, stream>>>(q16, k16, vt16, a16);
    // 4) proj GEMM (M=256, K=64) -> c16
    gemm_f16<256, 64, 1><<<dim3(576), blk, 0, stream>>>(
        Ap, a16, pr_b, pi_b, nullptr, nullptr, c16, nullptr, nullptr, nullptr, nullptr, nullptr);
    // 5) post-LN + build gate input Xg = [f16(f) | f16(LN(c))] (XCD-affine)
    ln_post<<<dim3(576), blk, 0, stream>>>(c16, pr_lnw, pr_lnb, pi_lnw, pi_lnb,
                                           f_rgb, f_ir, Xg);
    // 6) gate GEMM (M=256, K=512) + sigmoid + residual -> out
    gemm_f16<256, 512, 2><<<dim3(576), blk, 0, stream>>>(
        Ag, Xg, gr_b, gi_b, nullptr, nullptr, nullptr, nullptr, nullptr, f_rgb, f_ir, outp);
}

// Round 13
// 104.299 us; speedup vs baseline: 3.1184x; 1.0714x over previous
//
#include <hip/hip_runtime.h>

static constexpr int kDim   = 256;
static constexpr int kInner = 64;
static constexpr int kNH    = 8;
static constexpr int kB     = 2;
static constexpr int kP     = 2304;   // 48*48
static constexpr float kScale = 0.35355339059327373f; // 8^-0.5
static constexpr float kEps   = 1e-6f;

typedef __fp16   fp16x2 __attribute__((ext_vector_type(2)));
typedef _Float16 half4f __attribute__((ext_vector_type(4)));
typedef _Float16 half8  __attribute__((ext_vector_type(8)));
typedef float    f32x4  __attribute__((ext_vector_type(4)));

// ws layout in halfs:
static constexpr size_t oXq  = 0;          // [4 combo][2304][256]      = 2359296
static constexpr size_t oQ16 = 2359296;    // [2 inp][16 bh][2304][8]   = 589824
static constexpr size_t oK16 = 2949120;    // same                      = 589824
static constexpr size_t oV16 = 3538944;    // [2 inp][16 bh][8][2304]   = 589824
static constexpr size_t oA16 = 4128768;    // [4 combo][2304][64]       = 589824
// Xg aliases [0 .. 4718592): [4 combo][2304][512]  (written after all above dead)
static constexpr size_t oC16 = 4718592;    // [4 combo][2304][256]      = 2359296
static constexpr size_t oW16 = 7077888;    // weights f16               = 393216
static constexpr size_t kInpStride = 294912; // q16/k16/vt16 per-inp stride (halfs)

// ---------------- prep: blocks <576 do pre-LN (XCD-affine); blocks >=576 cast weights.
__global__ __launch_bounds__(256) void prep(
    const float* __restrict__ x0, const float* __restrict__ w0,
    const float* __restrict__ b0, const float* __restrict__ x1,
    const float* __restrict__ w1, const float* __restrict__ b1,
    _Float16* __restrict__ Xq,
    const float* __restrict__ qr_w, const float* __restrict__ kvr_w,
    const float* __restrict__ qi_w, const float* __restrict__ kvi_w,
    const float* __restrict__ pr_w, const float* __restrict__ pi_w,
    const float* __restrict__ gr_w, const float* __restrict__ gi_w,
    _Float16* __restrict__ w16)
{
    if (blockIdx.x >= 576) {               // weight cast
        const int flat = blockIdx.x - 576;
        const int y = flat >> 6, x = flat & 63;
        const float* src; _Float16* dst; int n;
        _Float16* Aq = w16;             // [2][192][256]
        _Float16* Ap = w16 + 98304;     // [2][256][64]
        _Float16* Ag = w16 + 131072;    // [2][256][512]
        switch (y) {
            case 0: src = qr_w;  dst = Aq;          n = 16384;  break;
            case 1: src = kvr_w; dst = Aq + 16384;  n = 32768;  break;
            case 2: src = qi_w;  dst = Aq + 49152;  n = 16384;  break;
            case 3: src = kvi_w; dst = Aq + 65536;  n = 32768;  break;
            case 4: src = pr_w;  dst = Ap;          n = 16384;  break;
            case 5: src = pi_w;  dst = Ap + 16384;  n = 16384;  break;
            case 6: src = gr_w;  dst = Ag;          n = 131072; break;
            default:src = gi_w;  dst = Ag + 131072; n = 131072; break;
        }
        for (int i = x * 256 + threadIdx.x; i < n; i += 64 * 256)
            dst[i] = (_Float16)src[i];
        return;
    }
    // pre-LN
    __shared__ float sb[16][16];
    __shared__ float ssb[16][16];
    const int fid = blockIdx.x;
    const int xcd = fid & 7, q = fid >> 3;      // q 0..71
    const int inp = (xcd >> 2) & 1, bb = (xcd >> 1) & 1, half = xcd & 1;
    const float* x = inp ? x1 : x0;
    const float* w = inp ? w1 : w0;
    const float* b = inp ? b1 : b0;
    const int pos = threadIdx.x & 15;
    const int grp = threadIdx.x >> 4;
    const int p   = half * 1152 + q * 16 + pos;
    const size_t base = (size_t)bb * kDim * kP + p;
    const int c0 = grp * 16;

    float v[16];
    float s = 0.f, ss = 0.f;
    #pragma unroll
    for (int j = 0; j < 16; ++j) {
        v[j] = x[base + (size_t)(c0 + j) * kP];
        s += v[j]; ss += v[j] * v[j];
    }
    sb[grp][pos] = s; ssb[grp][pos] = ss;
    __syncthreads();
    float st = 0.f, sst = 0.f;
    #pragma unroll
    for (int g = 0; g < 16; ++g) { st += sb[g][pos]; sst += ssb[g][pos]; }
    const float mean = st * (1.f / kDim);
    const float rstd = rsqrtf(sst * (1.f / kDim) - mean * mean + kEps);
    half8 h0, h1;
    #pragma unroll
    for (int j = 0; j < 8; ++j) {
        h0[j] = (_Float16)((v[j]     - mean) * rstd * w[c0 + j]     + b[c0 + j]);
        h1[j] = (_Float16)((v[j + 8] - mean) * rstd * w[c0 + j + 8] + b[c0 + j + 8]);
    }
    _Float16* dst = Xq + ((size_t)(inp * 2 + bb) * kP + p) * 256 + c0;
    *(half8*)dst       = h0;
    *(half8*)(dst + 8) = h1;
}

// ---------------- post-LN: c16 -> LN -> Xg[..][256..512); raw f -> Xg[..][0..256).
// XCD-affine flat grid (576): fid&7 -> (s,bb,half) — SAME mapping as gate gemm.
__global__ __launch_bounds__(256) void ln_post(
    const _Float16* __restrict__ c16,
    const float* __restrict__ w0, const float* __restrict__ b0,
    const float* __restrict__ w1, const float* __restrict__ b1,
    const float* __restrict__ f0, const float* __restrict__ f1,
    _Float16* __restrict__ Xg)
{
    __shared__ float sb[16][16];
    __shared__ float ssb[16][16];
    const int fid = blockIdx.x;
    const int xcd = fid & 7, q = fid >> 3;      // q 0..71
    const int s = (xcd >> 2) & 1, bb = (xcd >> 1) & 1, half = xcd & 1;
    const float* w = s ? w1 : w0;
    const float* b = s ? b1 : b0;
    const float* F = s ? f1 : f0;
    const int pos = threadIdx.x & 15;
    const int grp = threadIdx.x >> 4;
    const int p   = half * 1152 + q * 16 + pos;
    const int c0  = grp * 16;
    const size_t combo = s * 2 + bb;

    const _Float16* cp = c16 + (combo * kP + p) * 256 + c0;
    const half8 g0 = *(const half8*)cp;
    const half8 g1 = *(const half8*)(cp + 8);
    float v[16];
    float sm = 0.f, ssq = 0.f;
    #pragma unroll
    for (int j = 0; j < 8; ++j) {
        v[j] = (float)g0[j]; v[j + 8] = (float)g1[j];
    }
    #pragma unroll
    for (int j = 0; j < 16; ++j) { sm += v[j]; ssq += v[j] * v[j]; }
    sb[grp][pos] = sm; ssb[grp][pos] = ssq;
    __syncthreads();
    float st = 0.f, sst = 0.f;
    #pragma unroll
    for (int g = 0; g < 16; ++g) { st += sb[g][pos]; sst += ssb[g][pos]; }
    const float mean = st * (1.f / kDim);
    const float rstd = rsqrtf(sst * (1.f / kDim) - mean * mean + kEps);

    _Float16* xrow = Xg + (combo * kP + p) * 512;
    half8 o0, o1;
    #pragma unroll
    for (int j = 0; j < 8; ++j) {
        o0[j] = (_Float16)((v[j]     - mean) * rstd * w[c0 + j]     + b[c0 + j]);
        o1[j] = (_Float16)((v[j + 8] - mean) * rstd * w[c0 + j + 8] + b[c0 + j + 8]);
    }
    *(half8*)(xrow + 256 + c0)     = o0;
    *(half8*)(xrow + 256 + c0 + 8) = o1;
    const size_t fbase = (size_t)bb * kDim * kP + p;
    half8 r0, r1;
    #pragma unroll
    for (int j = 0; j < 8; ++j) {
        r0[j] = (_Float16)F[fbase + (size_t)(c0 + j) * kP];
        r1[j] = (_Float16)F[fbase + (size_t)(c0 + j + 8) * kP];
    }
    *(half8*)(xrow + c0)     = r0;
    *(half8*)(xrow + c0 + 8) = r1;
}

// ---------------- f16 MFMA GEMM, 64o x 64p block tile, 4 acc-chains per wave.
// XCD-affine flat grid: fid&7 -> (s,bb,half); fid>>3 -> (o-tile64, p-tile64).
// EPI: 0 = qkv routing, 1 = proj (c16), 2 = gate (sigmoid+residual f32).
template <int M, int K, int EPI>
__global__ __launch_bounds__(256) void gemm_f16(
    const _Float16* __restrict__ A,     // [2][M][K] f16 weights
    const _Float16* __restrict__ B,     // [4][2304][K] f16 activations
    const float* __restrict__ b0, const float* __restrict__ b1,
    const float* __restrict__ b2, const float* __restrict__ b3,
    _Float16* __restrict__ o16a, _Float16* __restrict__ o16b, _Float16* __restrict__ o16c,
    const float* __restrict__ f0, const float* __restrict__ f1,
    float* __restrict__ outp)
{
    constexpr int MT64 = M / 64;
    const int fid = blockIdx.x;
    const int xcd = fid & 7, q = fid >> 3;
    const int s = (xcd >> 2) & 1, bb = (xcd >> 1) & 1, half = xcd & 1;
    const int ot64 = (q % MT64) * 64;
    const int pt   = q / MT64;                 // 0..17
    const int wv = threadIdx.x >> 6, lane = threadIdx.x & 63;
    const int r16 = lane & 15, g = lane >> 4;
    const int ot = ot64 + wv * 16;             // wave's 16-o tile
    const int p0 = half * 1152 + pt * 64;      // block's 64-p tile
    const int combo = s * 2 + bb;

    const _Float16* Ar = A + ((size_t)s * M + ot + r16) * K + 8 * g;
    const _Float16* Br = B + ((size_t)combo * kP + p0 + r16) * K + 8 * g;
    f32x4 acc0[4], acc1[4];
    #pragma unroll
    for (int ps = 0; ps < 4; ++ps) {
        acc0[ps] = (f32x4){0.f, 0.f, 0.f, 0.f};
        acc1[ps] = (f32x4){0.f, 0.f, 0.f, 0.f};
    }
    #pragma unroll 4
    for (int c0 = 0; c0 < K; c0 += 32) {
        const half8 a8 = *(const half8*)(Ar + c0);
        half8 b8[4];
        #pragma unroll
        for (int ps = 0; ps < 4; ++ps)
            b8[ps] = *(const half8*)(Br + (size_t)(16 * ps) * K + c0);
        const half4f al = {a8[0], a8[1], a8[2], a8[3]};
        const half4f ah = {a8[4], a8[5], a8[6], a8[7]};
        #pragma unroll
        for (int ps = 0; ps < 4; ++ps) {
            const half4f bl = {b8[ps][0], b8[ps][1], b8[ps][2], b8[ps][3]};
            const half4f bh = {b8[ps][4], b8[ps][5], b8[ps][6], b8[ps][7]};
            acc0[ps] = __builtin_amdgcn_mfma_f32_16x16x16f16(al, bl, acc0[ps], 0, 0, 0);
            acc1[ps] = __builtin_amdgcn_mfma_f32_16x16x16f16(ah, bh, acc1[ps], 0, 0, 0);
        }
    }
    const int obase = ot + 4 * g;              // o = obase + i

    #pragma unroll
    for (int ps = 0; ps < 4; ++ps) {
        float acc[4];
        #pragma unroll
        for (int i = 0; i < 4; ++i) acc[i] = acc0[ps][i] + acc1[ps][i];
        const int p = p0 + 16 * ps + r16;

        if constexpr (EPI == 0) {              // qkv: ot64 0 = q, 64 = k, 128 = v
            const int dlo = 4 * (g & 1);
            if (ot < 64) {
                const float* qb = s ? b1 : b0;
                const float4 bv = *(const float4*)(qb + obase);
                const int h = (ot >> 3) + (g >> 1);
                half4f o = { (_Float16)((acc[0] + bv.x) * kScale), (_Float16)((acc[1] + bv.y) * kScale),
                             (_Float16)((acc[2] + bv.z) * kScale), (_Float16)((acc[3] + bv.w) * kScale) };
                *(half4f*)(o16a + (((size_t)combo * 8 + h) * kP + p) * 8 + dlo) = o;
            } else if (ot < 128) {
                const float* kb = s ? b3 : b2;
                const float4 bv = *(const float4*)(kb + obase - 64);
                const int h = ((ot - 64) >> 3) + (g >> 1);
                half4f o = { (_Float16)(acc[0] + bv.x), (_Float16)(acc[1] + bv.y),
                             (_Float16)(acc[2] + bv.z), (_Float16)(acc[3] + bv.w) };
                *(half4f*)(o16b + (((size_t)combo * 8 + h) * kP + p) * 8 + dlo) = o;
            } else {
                const float* kb = s ? b3 : b2;
                const float4 bv = *(const float4*)(kb + obase - 64);
                const int h = ((ot - 128) >> 3) + (g >> 1);
                const float* bvp = (const float*)&bv;
                #pragma unroll
                for (int i = 0; i < 4; ++i)
                    o16c[(((size_t)combo * 8 + h) * 8 + dlo + i) * kP + p] = (_Float16)(acc[i] + bvp[i]);
            }
        } else if constexpr (EPI == 1) {       // proj -> c16 [combo][p][256]
            const float* pb = s ? b1 : b0;
            const float4 bv = *(const float4*)(pb + obase);
            half4f o = { (_Float16)(acc[0] + bv.x), (_Float16)(acc[1] + bv.y),
                         (_Float16)(acc[2] + bv.z), (_Float16)(acc[3] + bv.w) };
            *(half4f*)(o16a + ((size_t)combo * kP + p) * 256 + obase) = o;
        } else {                               // gate: sigmoid + residual -> f32 out
            const float* gb = s ? b1 : b0;
            const float4 bv = *(const float4*)(gb + obase);
            const float* bvp = (const float*)&bv;
            const half4f cx = *(const half4f*)(B + ((size_t)combo * kP + p) * 512 + 256 + obase);
            const float* F = s ? f1 : f0;
            #pragma unroll
            for (int i = 0; i < 4; ++i) {
                const int o = obase + i;
                const float gt = 1.f / (1.f + __expf(-(acc[i] + bvp[i])));
                const float fb = F[((size_t)bb * kDim + o) * kP + p];
                outp[((size_t)combo * kDim + o) * kP + p] = fb + gt * (float)cx[i];
            }
        }
    }
}

// ---------------- fused MFMA flash attention: frag-order LDS (V padded to 66
// slots/kt to kill the 16-way V-write conflict), reg double-buffered staging.
// grid (36, 16, 2): x = q-tile of 64, y = bh, z = stream. block 256 = 4 waves x 16 q.
__global__ __launch_bounds__(256) void attn_mfma(
    const _Float16* __restrict__ q16, const _Float16* __restrict__ k16,
    const _Float16* __restrict__ vt16, _Float16* __restrict__ a16)
{
    __shared__ _Float16 Ksm[16 * 64 * 4];   // [kt][slot 0..63] 8B frags (512B/kt)
    __shared__ _Float16 Vsm[16 * 66 * 4];   // [kt][slot 0..63] 8B frags, 66-slot pitch
    const int st = blockIdx.z;
    const _Float16* Qg = q16  + (size_t)st * kInpStride;
    const _Float16* Kg = k16  + (size_t)(1 - st) * kInpStride;
    const _Float16* Vg = vt16 + (size_t)(1 - st) * kInpStride;
    const int bh = blockIdx.y;
    const int bb = bh >> 3, h = bh & 7;
    const int tid  = threadIdx.x;
    const int wv   = tid >> 6;
    const int lane = tid & 63;
    const int r16  = lane & 15;
    const int g    = lane >> 4;

    // prefill static pad slots: K slots 32..63 = 0; V slots with (slot&15)>=8
    // (row 8 = ones for the rowsum trick, rows 9..15 = 0)
    #pragma unroll
    for (int j = 0; j < 2; ++j) {
        const int s = tid + 256 * j;            // 0..511
        const int kt = s >> 5, m = s & 31;
        *(half4f*)(Ksm + (kt * 64 + 32 + m) * 4) = (half4f){0, 0, 0, 0};
        const int rv = 8 + (m & 7), gv = m >> 3;
        const half4f vv = (rv == 8)
            ? (half4f){(_Float16)1.f, (_Float16)1.f, (_Float16)1.f, (_Float16)1.f}
            : (half4f){0, 0, 0, 0};
        *(half4f*)(Vsm + (kt * 66 + gv * 16 + rv) * 4) = vv;
    }

    const int qg = blockIdx.x * 64 + wv * 16 + r16;
    half4f qf = (half4f){0, 0, 0, 0};
    if (g < 2) qf = *(const half4f*)(Qg + ((size_t)bh * kP + qg) * 8 + g * 4);

    // staging coords (fixed per thread)
    const int vd = tid >> 5, vc8 = (tid & 31) * 8;
    const int vkt = vc8 >> 4, vgv = (vc8 & 15) >> 2;       // vgv in {0, 2}
    _Float16* kdst = Ksm + ((tid >> 4) * 64 + (tid & 15)) * 4;
    _Float16* vdst = Vsm + (vkt * 66 + vgv * 16 + vd) * 4;
    const _Float16* ksrc = Kg + ((size_t)bh * kP + tid) * 8;
    const _Float16* vsrc = Vg + (size_t)(bh * 8 + vd) * kP + vc8;

    // preload chunk 0
    half8 kreg = *(const half8*)ksrc;
    half8 vreg = *(const half8*)vsrc;

    f32x4 of = (f32x4){0.f, 0.f, 0.f, 0.f};

    for (int ch = 0; ch < 9; ++ch) {
        if (ch) __syncthreads();                // prev compute done before re-stage
        // write staged regs -> LDS
        *(half4f*)kdst        = (half4f){kreg[0], kreg[1], kreg[2], kreg[3]};
        *(half4f*)(kdst + 64) = (half4f){kreg[4], kreg[5], kreg[6], kreg[7]};
        *(half4f*)vdst        = (half4f){vreg[0], vreg[1], vreg[2], vreg[3]};
        *(half4f*)(vdst + 64) = (half4f){vreg[4], vreg[5], vreg[6], vreg[7]};
        __syncthreads();
        // prefetch next chunk (latency hides under the 16-kt compute below)
        if (ch < 8) {
            kreg = *(const half8*)(ksrc + (size_t)(ch + 1) * 2048);   // 256 keys * 8 halfs
            vreg = *(const half8*)(vsrc + (size_t)(ch + 1) * 256);    // 256 cols
        }
        #pragma unroll
        for (int kt = 0; kt < 16; ++kt) {
            const half4f kf = *(const half4f*)(Ksm + (kt * 64 + lane) * 4);
            f32x4 sv = __builtin_amdgcn_mfma_f32_16x16x16f16(kf, qf, (f32x4){0.f,0.f,0.f,0.f}, 0, 0, 0);
            const float e0 = __expf(sv[0]), e1 = __expf(sv[1]);
            const float e2 = __expf(sv[2]), e3 = __expf(sv[3]);
            const fp16x2 lo = __builtin_amdgcn_cvt_pkrtz(e0, e1);
            const fp16x2 hi = __builtin_amdgcn_cvt_pkrtz(e2, e3);
            const half4f pf = { (_Float16)lo[0], (_Float16)lo[1],
                                (_Float16)hi[0], (_Float16)hi[1] };
            const half4f vf = *(const half4f*)(Vsm + (kt * 66 + lane) * 4);
            of = __builtin_amdgcn_mfma_f32_16x16x16f16(vf, pf, of, 0, 0, 0);
        }
    }
    // rowsum lives in PV output row 8 = lane (g=2, r16), reg 0
    const float rsv = __shfl(of[0], 32 + r16, 64);
    const float inv = 1.f / rsv;
    if (g < 2) {   // lane holds d = h*8 + 4g + i at position qg
        half4f o = { (_Float16)(of[0] * inv), (_Float16)(of[1] * inv),
                     (_Float16)(of[2] * inv), (_Float16)(of[3] * inv) };
        *(half4f*)(a16 + ((size_t)(st * 2 + bb) * kP + qg) * 64 + h * 8 + g * 4) = o;
    }
}

extern "C" void kernel_launch(void* const* d_in, const int* in_sizes, int n_in,
                              void* d_out, int out_size, void* d_ws, size_t ws_size,
                              hipStream_t stream)
{
    const float* f_rgb  = (const float*)d_in[0];
    const float* f_ir   = (const float*)d_in[1];
    const float* nr_w   = (const float*)d_in[2];
    const float* nr_b   = (const float*)d_in[3];
    const float* ni_w   = (const float*)d_in[4];
    const float* ni_b   = (const float*)d_in[5];
    const float* qr_w   = (const float*)d_in[6];
    const float* qr_b   = (const float*)d_in[7];
    const float* kvi_w  = (const float*)d_in[8];
    const float* kvi_b  = (const float*)d_in[9];
    const float* qi_w   = (const float*)d_in[10];
    const float* qi_b   = (const float*)d_in[11];
    const float* kvr_w  = (const float*)d_in[12];
    const float* kvr_b  = (const float*)d_in[13];
    const float* pr_w   = (const float*)d_in[14];
    const float* pr_b   = (const float*)d_in[15];
    const float* pr_lnw = (const float*)d_in[16];
    const float* pr_lnb = (const float*)d_in[17];
    const float* pi_w   = (const float*)d_in[18];
    const float* pi_b   = (const float*)d_in[19];
    const float* pi_lnw = (const float*)d_in[20];
    const float* pi_lnb = (const float*)d_in[21];
    const float* gr_w   = (const float*)d_in[22];
    const float* gr_b   = (const float*)d_in[23];
    const float* gi_w   = (const float*)d_in[24];
    const float* gi_b   = (const float*)d_in[25];

    _Float16* hb   = (_Float16*)d_ws;
    _Float16* Xq   = hb + oXq;
    _Float16* q16  = hb + oQ16;
    _Float16* k16  = hb + oK16;
    _Float16* vt16 = hb + oV16;
    _Float16* a16  = hb + oA16;
    _Float16* Xg   = hb;            // aliases [Xq|q16|k16|vt16|a16] (dead by then)
    _Float16* c16  = hb + oC16;
    _Float16* W16  = hb + oW16;
    _Float16* Aq   = W16;           // [2][192][256]
    _Float16* Ap   = W16 + 98304;   // [2][256][64]
    _Float16* Ag   = W16 + 131072;  // [2][256][512]

    float* outp = (float*)d_out;
    const dim3 blk(256);

    // 1) pre-LN (XCD-affine) + weight cast in one launch
    prep<<<dim3(1088), blk, 0, stream>>>(f_rgb, nr_w, nr_b, f_ir, ni_w, ni_b, Xq,
                                         qr_w, kvr_w, qi_w, kvi_w, pr_w, pi_w, gr_w, gi_w, W16);
    // 2) qkv GEMM (M=192, K=256)
    gemm_f16<192, 256, 0><<<dim3(432), blk, 0, stream>>>(
        Aq, Xq, qr_b, qi_b, kvr_b, kvi_b, q16, k16, vt16, nullptr, nullptr, nullptr);
    // 3) fused MFMA attention -> a16 pos-major
    attn_mfma<<<dim3(36, 16, 2), blk, 0, stream>>>(q16, k16, vt16, a16);
    // 4) proj GEMM (M=256, K=64) -> c16
    gemm_f16<256, 64, 1><<<dim3(576), blk, 0, stream>>>(
        Ap, a16, pr_b, pi_b, nullptr, nullptr, c16, nullptr, nullptr, nullptr, nullptr, nullptr);
    // 5) post-LN + build gate input Xg = [f16(f) | f16(LN(c))] (XCD-affine)
    ln_post<<<dim3(576), blk, 0, stream>>>(c16, pr_lnw, pr_lnb, pi_lnw, pi_lnb,
                                           f_rgb, f_ir, Xg);
    // 6) gate GEMM (M=256, K=512) + sigmoid + residual -> out
    gemm_f16<256, 512, 2><<<dim3(576), blk, 0, stream>>>(
        Ag, Xg, gr_b, gi_b, nullptr, nullptr, nullptr, nullptr, nullptr, f_rgb, f_ir, outp);
}

// Round 14
// 101.804 us; speedup vs baseline: 3.1948x; 1.0245x over previous
//
#include <hip/hip_runtime.h>

static constexpr int kDim   = 256;
static constexpr int kInner = 64;
static constexpr int kNH    = 8;
static constexpr int kB     = 2;
static constexpr int kP     = 2304;   // 48*48
static constexpr float kScale = 0.35355339059327373f; // 8^-0.5
static constexpr float kEps   = 1e-6f;

typedef __fp16   fp16x2 __attribute__((ext_vector_type(2)));
typedef _Float16 half4f __attribute__((ext_vector_type(4)));
typedef _Float16 half8  __attribute__((ext_vector_type(8)));
typedef float    f32x4  __attribute__((ext_vector_type(4)));

// ws layout in halfs:
static constexpr size_t oXq  = 0;          // [4 combo][2304][256]      = 2359296
static constexpr size_t oQ16 = 2359296;    // [2 inp][16 bh][2304][8]   = 589824
static constexpr size_t oK16 = 2949120;    // same                      = 589824
static constexpr size_t oV16 = 3538944;    // [2 inp][16 bh][8][2304]   = 589824
static constexpr size_t oA16 = 4128768;    // [4 combo][2304][64]       = 589824
// Xg aliases [0 .. 4718592): [4 combo][2304][512]  (written after all above dead)
static constexpr size_t oW16 = 7077888;    // weights f16               = 393216
static constexpr size_t kInpStride = 294912; // q16/k16/vt16 per-inp stride (halfs)

// ---------------- prep: blocks <576 do pre-LN (XCD-affine); blocks >=576 cast weights.
__global__ __launch_bounds__(256) void prep(
    const float* __restrict__ x0, const float* __restrict__ w0,
    const float* __restrict__ b0, const float* __restrict__ x1,
    const float* __restrict__ w1, const float* __restrict__ b1,
    _Float16* __restrict__ Xq,
    const float* __restrict__ qr_w, const float* __restrict__ kvr_w,
    const float* __restrict__ qi_w, const float* __restrict__ kvi_w,
    const float* __restrict__ pr_w, const float* __restrict__ pi_w,
    const float* __restrict__ gr_w, const float* __restrict__ gi_w,
    _Float16* __restrict__ w16)
{
    if (blockIdx.x >= 576) {               // weight cast
        const int flat = blockIdx.x - 576;
        const int y = flat >> 6, x = flat & 63;
        const float* src; _Float16* dst; int n;
        _Float16* Aq = w16;             // [2][192][256]
        _Float16* Ap = w16 + 98304;     // [2][256][64]
        _Float16* Ag = w16 + 131072;    // [2][256][512]
        switch (y) {
            case 0: src = qr_w;  dst = Aq;          n = 16384;  break;
            case 1: src = kvr_w; dst = Aq + 16384;  n = 32768;  break;
            case 2: src = qi_w;  dst = Aq + 49152;  n = 16384;  break;
            case 3: src = kvi_w; dst = Aq + 65536;  n = 32768;  break;
            case 4: src = pr_w;  dst = Ap;          n = 16384;  break;
            case 5: src = pi_w;  dst = Ap + 16384;  n = 16384;  break;
            case 6: src = gr_w;  dst = Ag;          n = 131072; break;
            default:src = gi_w;  dst = Ag + 131072; n = 131072; break;
        }
        for (int i = x * 256 + threadIdx.x; i < n; i += 64 * 256)
            dst[i] = (_Float16)src[i];
        return;
    }
    // pre-LN
    __shared__ float sb[16][16];
    __shared__ float ssb[16][16];
    const int fid = blockIdx.x;
    const int xcd = fid & 7, q = fid >> 3;      // q 0..71
    const int inp = (xcd >> 2) & 1, bb = (xcd >> 1) & 1, half = xcd & 1;
    const float* x = inp ? x1 : x0;
    const float* w = inp ? w1 : w0;
    const float* b = inp ? b1 : b0;
    const int pos = threadIdx.x & 15;
    const int grp = threadIdx.x >> 4;
    const int p   = half * 1152 + q * 16 + pos;
    const size_t base = (size_t)bb * kDim * kP + p;
    const int c0 = grp * 16;

    float v[16];
    float s = 0.f, ss = 0.f;
    #pragma unroll
    for (int j = 0; j < 16; ++j) {
        v[j] = x[base + (size_t)(c0 + j) * kP];
        s += v[j]; ss += v[j] * v[j];
    }
    sb[grp][pos] = s; ssb[grp][pos] = ss;
    __syncthreads();
    float st = 0.f, sst = 0.f;
    #pragma unroll
    for (int g = 0; g < 16; ++g) { st += sb[g][pos]; sst += ssb[g][pos]; }
    const float mean = st * (1.f / kDim);
    const float rstd = rsqrtf(sst * (1.f / kDim) - mean * mean + kEps);
    half8 h0, h1;
    #pragma unroll
    for (int j = 0; j < 8; ++j) {
        h0[j] = (_Float16)((v[j]     - mean) * rstd * w[c0 + j]     + b[c0 + j]);
        h1[j] = (_Float16)((v[j + 8] - mean) * rstd * w[c0 + j + 8] + b[c0 + j + 8]);
    }
    _Float16* dst = Xq + ((size_t)(inp * 2 + bb) * kP + p) * 256 + c0;
    *(half8*)dst       = h0;
    *(half8*)(dst + 8) = h1;
}

// ---------------- f16 MFMA GEMM, 64o x 64p block tile, 4 acc-chains per wave.
// XCD-affine flat grid: fid&7 -> (s,bb,half); fid>>3 -> (o-tile64, p-tile64).
// EPI: 0 = qkv routing, 2 = gate (sigmoid+residual f32).
template <int M, int K, int EPI>
__global__ __launch_bounds__(256) void gemm_f16(
    const _Float16* __restrict__ A,     // [2][M][K] f16 weights
    const _Float16* __restrict__ B,     // [4][2304][K] f16 activations
    const float* __restrict__ b0, const float* __restrict__ b1,
    const float* __restrict__ b2, const float* __restrict__ b3,
    _Float16* __restrict__ o16a, _Float16* __restrict__ o16b, _Float16* __restrict__ o16c,
    const float* __restrict__ f0, const float* __restrict__ f1,
    float* __restrict__ outp)
{
    constexpr int MT64 = M / 64;
    const int fid = blockIdx.x;
    const int xcd = fid & 7, q = fid >> 3;
    const int s = (xcd >> 2) & 1, bb = (xcd >> 1) & 1, half = xcd & 1;
    const int ot64 = (q % MT64) * 64;
    const int pt   = q / MT64;                 // 0..17
    const int wv = threadIdx.x >> 6, lane = threadIdx.x & 63;
    const int r16 = lane & 15, g = lane >> 4;
    const int ot = ot64 + wv * 16;             // wave's 16-o tile
    const int p0 = half * 1152 + pt * 64;      // block's 64-p tile
    const int combo = s * 2 + bb;

    const _Float16* Ar = A + ((size_t)s * M + ot + r16) * K + 8 * g;
    const _Float16* Br = B + ((size_t)combo * kP + p0 + r16) * K + 8 * g;
    f32x4 acc0[4], acc1[4];
    #pragma unroll
    for (int ps = 0; ps < 4; ++ps) {
        acc0[ps] = (f32x4){0.f, 0.f, 0.f, 0.f};
        acc1[ps] = (f32x4){0.f, 0.f, 0.f, 0.f};
    }
    #pragma unroll 4
    for (int c0 = 0; c0 < K; c0 += 32) {
        const half8 a8 = *(const half8*)(Ar + c0);
        half8 b8[4];
        #pragma unroll
        for (int ps = 0; ps < 4; ++ps)
            b8[ps] = *(const half8*)(Br + (size_t)(16 * ps) * K + c0);
        const half4f al = {a8[0], a8[1], a8[2], a8[3]};
        const half4f ah = {a8[4], a8[5], a8[6], a8[7]};
        #pragma unroll
        for (int ps = 0; ps < 4; ++ps) {
            const half4f bl = {b8[ps][0], b8[ps][1], b8[ps][2], b8[ps][3]};
            const half4f bh = {b8[ps][4], b8[ps][5], b8[ps][6], b8[ps][7]};
            acc0[ps] = __builtin_amdgcn_mfma_f32_16x16x16f16(al, bl, acc0[ps], 0, 0, 0);
            acc1[ps] = __builtin_amdgcn_mfma_f32_16x16x16f16(ah, bh, acc1[ps], 0, 0, 0);
        }
    }
    const int obase = ot + 4 * g;              // o = obase + i

    #pragma unroll
    for (int ps = 0; ps < 4; ++ps) {
        float acc[4];
        #pragma unroll
        for (int i = 0; i < 4; ++i) acc[i] = acc0[ps][i] + acc1[ps][i];
        const int p = p0 + 16 * ps + r16;

        if constexpr (EPI == 0) {              // qkv: ot64 0 = q, 64 = k, 128 = v
            const int dlo = 4 * (g & 1);
            if (ot < 64) {
                const float* qb = s ? b1 : b0;
                const float4 bv = *(const float4*)(qb + obase);
                const int h = (ot >> 3) + (g >> 1);
                half4f o = { (_Float16)((acc[0] + bv.x) * kScale), (_Float16)((acc[1] + bv.y) * kScale),
                             (_Float16)((acc[2] + bv.z) * kScale), (_Float16)((acc[3] + bv.w) * kScale) };
                *(half4f*)(o16a + (((size_t)combo * 8 + h) * kP + p) * 8 + dlo) = o;
            } else if (ot < 128) {
                const float* kb = s ? b3 : b2;
                const float4 bv = *(const float4*)(kb + obase - 64);
                const int h = ((ot - 64) >> 3) + (g >> 1);
                half4f o = { (_Float16)(acc[0] + bv.x), (_Float16)(acc[1] + bv.y),
                             (_Float16)(acc[2] + bv.z), (_Float16)(acc[3] + bv.w) };
                *(half4f*)(o16b + (((size_t)combo * 8 + h) * kP + p) * 8 + dlo) = o;
            } else {
                const float* kb = s ? b3 : b2;
                const float4 bv = *(const float4*)(kb + obase - 64);
                const int h = ((ot - 128) >> 3) + (g >> 1);
                const float* bvp = (const float*)&bv;
                #pragma unroll
                for (int i = 0; i < 4; ++i)
                    o16c[(((size_t)combo * 8 + h) * 8 + dlo + i) * kP + p] = (_Float16)(acc[i] + bvp[i]);
            }
        } else {                               // gate: sigmoid + residual -> f32 out
            const float* gb = s ? b1 : b0;
            const float4 bv = *(const float4*)(gb + obase);
            const float* bvp = (const float*)&bv;
            const half4f cx = *(const half4f*)(B + ((size_t)combo * kP + p) * 512 + 256 + obase);
            const float* F = s ? f1 : f0;
            #pragma unroll
            for (int i = 0; i < 4; ++i) {
                const int o = obase + i;
                const float gt = 1.f / (1.f + __expf(-(acc[i] + bvp[i])));
                const float fb = F[((size_t)bb * kDim + o) * kP + p];
                outp[((size_t)combo * kDim + o) * kP + p] = fb + gt * (float)cx[i];
            }
        }
    }
}

// ---------------- fused proj GEMM (K=64, M=256) + LN + Xg build.
// XCD-affine flat grid (576): fid&7 -> (s,bb,half); fid>>3 -> 16-pos chunk.
// Block: 4 waves, wave wv computes o in [wv*64, wv*64+64) for 16 positions.
// Epilogue: in-block LN over all 256 channels, write Xg[..][256..512); also
// cast raw f into Xg[..][0..256).
__global__ __launch_bounds__(256) void proj_ln(
    const _Float16* __restrict__ a16, const _Float16* __restrict__ Ap,
    const float* __restrict__ pb0, const float* __restrict__ pb1,
    const float* __restrict__ w0, const float* __restrict__ b0,
    const float* __restrict__ w1, const float* __restrict__ b1,
    const float* __restrict__ f0, const float* __restrict__ f1,
    _Float16* __restrict__ Xg)
{
    __shared__ float sb[4][4][16];
    __shared__ float ssb[4][4][16];
    const int fid = blockIdx.x;
    const int xcd = fid & 7, q = fid >> 3;      // q 0..71
    const int s = (xcd >> 2) & 1, bb = (xcd >> 1) & 1, half = xcd & 1;
    const int wv = threadIdx.x >> 6, lane = threadIdx.x & 63;
    const int r16 = lane & 15, g = lane >> 4;
    const int p = half * 1152 + q * 16 + r16;
    const int combo = s * 2 + bb;
    const float* pb = s ? pb1 : pb0;
    const float* w  = s ? w1 : w0;
    const float* b  = s ? b1 : b0;
    const float* F  = s ? f1 : f0;

    // B frags (shared across the wave's 4 o-tiles)
    const _Float16* Br = a16 + ((size_t)combo * kP + p) * 64 + 8 * g;
    const half8 bA = *(const half8*)Br;
    const half8 bB = *(const half8*)(Br + 32);
    const half4f bl0 = {bA[0], bA[1], bA[2], bA[3]};
    const half4f bh0 = {bA[4], bA[5], bA[6], bA[7]};
    const half4f bl1 = {bB[0], bB[1], bB[2], bB[3]};
    const half4f bh1 = {bB[4], bB[5], bB[6], bB[7]};

    float cval[4][4];
    float psum = 0.f, psq = 0.f;
    #pragma unroll
    for (int t = 0; t < 4; ++t) {
        const int ot = wv * 64 + t * 16;
        const _Float16* Ar = Ap + ((size_t)s * 256 + ot + r16) * 64 + 8 * g;
        const half8 aA = *(const half8*)Ar;
        const half8 aB = *(const half8*)(Ar + 32);
        const half4f al0 = {aA[0], aA[1], aA[2], aA[3]};
        const half4f ah0 = {aA[4], aA[5], aA[6], aA[7]};
        const half4f al1 = {aB[0], aB[1], aB[2], aB[3]};
        const half4f ah1 = {aB[4], aB[5], aB[6], aB[7]};
        f32x4 acc0 = __builtin_amdgcn_mfma_f32_16x16x16f16(al0, bl0, (f32x4){0.f,0.f,0.f,0.f}, 0, 0, 0);
        acc0 = __builtin_amdgcn_mfma_f32_16x16x16f16(al1, bl1, acc0, 0, 0, 0);
        f32x4 acc1 = __builtin_amdgcn_mfma_f32_16x16x16f16(ah0, bh0, (f32x4){0.f,0.f,0.f,0.f}, 0, 0, 0);
        acc1 = __builtin_amdgcn_mfma_f32_16x16x16f16(ah1, bh1, acc1, 0, 0, 0);
        const float4 bv = *(const float4*)(pb + ot + 4 * g);
        const float* bvp = (const float*)&bv;
        #pragma unroll
        for (int i = 0; i < 4; ++i) {
            const float v = acc0[i] + acc1[i] + bvp[i];
            cval[t][i] = v;
            psum += v; psq += v * v;
        }
    }
    sb[wv][g][r16] = psum; ssb[wv][g][r16] = psq;
    __syncthreads();
    float st = 0.f, sst = 0.f;
    #pragma unroll
    for (int w2 = 0; w2 < 4; ++w2)
        #pragma unroll
        for (int g2 = 0; g2 < 4; ++g2) { st += sb[w2][g2][r16]; sst += ssb[w2][g2][r16]; }
    const float mean = st * (1.f / kDim);
    const float rstd = rsqrtf(sst * (1.f / kDim) - mean * mean + kEps);

    _Float16* xrow = Xg + ((size_t)combo * kP + p) * 512;
    #pragma unroll
    for (int t = 0; t < 4; ++t) {
        const int o4 = wv * 64 + t * 16 + 4 * g;
        const float4 lw = *(const float4*)(w + o4);
        const float4 lb = *(const float4*)(b + o4);
        const float* lwp = (const float*)&lw;
        const float* lbp = (const float*)&lb;
        half4f o;
        #pragma unroll
        for (int i = 0; i < 4; ++i)
            o[i] = (_Float16)((cval[t][i] - mean) * rstd * lwp[i] + lbp[i]);
        *(half4f*)(xrow + 256 + o4) = o;
        // raw f cast for the same channels
        half4f r;
        #pragma unroll
        for (int i = 0; i < 4; ++i)
            r[i] = (_Float16)F[((size_t)bb * kDim + o4 + i) * kP + p];
        *(half4f*)(xrow + o4) = r;
    }
}

// ---------------- fused MFMA flash attention: frag-order LDS (V 66-slot pitch),
// reg double-buffered staging, dual PV accumulators (even/odd kt) for ILP.
// grid (36, 16, 2): x = q-tile of 64, y = bh, z = stream. block 256 = 4 waves x 16 q.
__global__ __launch_bounds__(256) void attn_mfma(
    const _Float16* __restrict__ q16, const _Float16* __restrict__ k16,
    const _Float16* __restrict__ vt16, _Float16* __restrict__ a16)
{
    __shared__ _Float16 Ksm[16 * 64 * 4];   // [kt][slot 0..63] 8B frags (512B/kt)
    __shared__ _Float16 Vsm[16 * 66 * 4];   // [kt][slot 0..63] 8B frags, 66-slot pitch
    const int st = blockIdx.z;
    const _Float16* Qg = q16  + (size_t)st * kInpStride;
    const _Float16* Kg = k16  + (size_t)(1 - st) * kInpStride;
    const _Float16* Vg = vt16 + (size_t)(1 - st) * kInpStride;
    const int bh = blockIdx.y;
    const int bb = bh >> 3, h = bh & 7;
    const int tid  = threadIdx.x;
    const int wv   = tid >> 6;
    const int lane = tid & 63;
    const int r16  = lane & 15;
    const int g    = lane >> 4;

    // prefill static pad slots: K slots 32..63 = 0; V slots with (slot&15)>=8
    // (row 8 = ones for the rowsum trick, rows 9..15 = 0)
    #pragma unroll
    for (int j = 0; j < 2; ++j) {
        const int s = tid + 256 * j;            // 0..511
        const int kt = s >> 5, m = s & 31;
        *(half4f*)(Ksm + (kt * 64 + 32 + m) * 4) = (half4f){0, 0, 0, 0};
        const int rv = 8 + (m & 7), gv = m >> 3;
        const half4f vv = (rv == 8)
            ? (half4f){(_Float16)1.f, (_Float16)1.f, (_Float16)1.f, (_Float16)1.f}
            : (half4f){0, 0, 0, 0};
        *(half4f*)(Vsm + (kt * 66 + gv * 16 + rv) * 4) = vv;
    }

    const int qg = blockIdx.x * 64 + wv * 16 + r16;
    half4f qf = (half4f){0, 0, 0, 0};
    if (g < 2) qf = *(const half4f*)(Qg + ((size_t)bh * kP + qg) * 8 + g * 4);

    // staging coords (fixed per thread)
    const int vd = tid >> 5, vc8 = (tid & 31) * 8;
    const int vkt = vc8 >> 4, vgv = (vc8 & 15) >> 2;       // vgv in {0, 2}
    _Float16* kdst = Ksm + ((tid >> 4) * 64 + (tid & 15)) * 4;
    _Float16* vdst = Vsm + (vkt * 66 + vgv * 16 + vd) * 4;
    const _Float16* ksrc = Kg + ((size_t)bh * kP + tid) * 8;
    const _Float16* vsrc = Vg + (size_t)(bh * 8 + vd) * kP + vc8;

    // preload chunk 0
    half8 kreg = *(const half8*)ksrc;
    half8 vreg = *(const half8*)vsrc;

    f32x4 of0 = (f32x4){0.f, 0.f, 0.f, 0.f};
    f32x4 of1 = (f32x4){0.f, 0.f, 0.f, 0.f};

    for (int ch = 0; ch < 9; ++ch) {
        if (ch) __syncthreads();                // prev compute done before re-stage
        *(half4f*)kdst        = (half4f){kreg[0], kreg[1], kreg[2], kreg[3]};
        *(half4f*)(kdst + 64) = (half4f){kreg[4], kreg[5], kreg[6], kreg[7]};
        *(half4f*)vdst        = (half4f){vreg[0], vreg[1], vreg[2], vreg[3]};
        *(half4f*)(vdst + 64) = (half4f){vreg[4], vreg[5], vreg[6], vreg[7]};
        __syncthreads();
        if (ch < 8) {
            kreg = *(const half8*)(ksrc + (size_t)(ch + 1) * 2048);   // 256 keys * 8 halfs
            vreg = *(const half8*)(vsrc + (size_t)(ch + 1) * 256);    // 256 cols
        }
        #pragma unroll
        for (int kt = 0; kt < 16; ++kt) {
            const half4f kf = *(const half4f*)(Ksm + (kt * 64 + lane) * 4);
            f32x4 sv = __builtin_amdgcn_mfma_f32_16x16x16f16(kf, qf, (f32x4){0.f,0.f,0.f,0.f}, 0, 0, 0);
            const float e0 = __expf(sv[0]), e1 = __expf(sv[1]);
            const float e2 = __expf(sv[2]), e3 = __expf(sv[3]);
            const fp16x2 lo = __builtin_amdgcn_cvt_pkrtz(e0, e1);
            const fp16x2 hi = __builtin_amdgcn_cvt_pkrtz(e2, e3);
            const half4f pf = { (_Float16)lo[0], (_Float16)lo[1],
                                (_Float16)hi[0], (_Float16)hi[1] };
            const half4f vf = *(const half4f*)(Vsm + (kt * 66 + lane) * 4);
            if (kt & 1) of1 = __builtin_amdgcn_mfma_f32_16x16x16f16(vf, pf, of1, 0, 0, 0);
            else        of0 = __builtin_amdgcn_mfma_f32_16x16x16f16(vf, pf, of0, 0, 0, 0);
        }
    }
    const f32x4 of = of0 + of1;
    // rowsum lives in PV output row 8 = lane (g=2, r16), reg 0
    const float rsv = __shfl(of[0], 32 + r16, 64);
    const float inv = 1.f / rsv;
    if (g < 2) {   // lane holds d = h*8 + 4g + i at position qg
        half4f o = { (_Float16)(of[0] * inv), (_Float16)(of[1] * inv),
                     (_Float16)(of[2] * inv), (_Float16)(of[3] * inv) };
        *(half4f*)(a16 + ((size_t)(st * 2 + bb) * kP + qg) * 64 + h * 8 + g * 4) = o;
    }
}

extern "C" void kernel_launch(void* const* d_in, const int* in_sizes, int n_in,
                              void* d_out, int out_size, void* d_ws, size_t ws_size,
                              hipStream_t stream)
{
    const float* f_rgb  = (const float*)d_in[0];
    const float* f_ir   = (const float*)d_in[1];
    const float* nr_w   = (const float*)d_in[2];
    const float* nr_b   = (const float*)d_in[3];
    const float* ni_w   = (const float*)d_in[4];
    const float* ni_b   = (const float*)d_in[5];
    const float* qr_w   = (const float*)d_in[6];
    const float* qr_b   = (const float*)d_in[7];
    const float* kvi_w  = (const float*)d_in[8];
    const float* kvi_b  = (const float*)d_in[9];
    const float* qi_w   = (const float*)d_in[10];
    const float* qi_b   = (const float*)d_in[11];
    const float* kvr_w  = (const float*)d_in[12];
    const float* kvr_b  = (const float*)d_in[13];
    const float* pr_w   = (const float*)d_in[14];
    const float* pr_b   = (const float*)d_in[15];
    const float* pr_lnw = (const float*)d_in[16];
    const float* pr_lnb = (const float*)d_in[17];
    const float* pi_w   = (const float*)d_in[18];
    const float* pi_b   = (const float*)d_in[19];
    const float* pi_lnw = (const float*)d_in[20];
    const float* pi_lnb = (const float*)d_in[21];
    const float* gr_w   = (const float*)d_in[22];
    const float* gr_b   = (const float*)d_in[23];
    const float* gi_w   = (const float*)d_in[24];
    const float* gi_b   = (const float*)d_in[25];

    _Float16* hb   = (_Float16*)d_ws;
    _Float16* Xq   = hb + oXq;
    _Float16* q16  = hb + oQ16;
    _Float16* k16  = hb + oK16;
    _Float16* vt16 = hb + oV16;
    _Float16* a16  = hb + oA16;
    _Float16* Xg   = hb;            // aliases [Xq|q16|k16|vt16] (dead by then; a16 is beyond)
    _Float16* W16  = hb + oW16;
    _Float16* Aq   = W16;           // [2][192][256]
    _Float16* Ap   = W16 + 98304;   // [2][256][64]
    _Float16* Ag   = W16 + 131072;  // [2][256][512]

    float* outp = (float*)d_out;
    const dim3 blk(256);

    // 1) pre-LN (XCD-affine) + weight cast in one launch
    prep<<<dim3(1088), blk, 0, stream>>>(f_rgb, nr_w, nr_b, f_ir, ni_w, ni_b, Xq,
                                         qr_w, kvr_w, qi_w, kvi_w, pr_w, pi_w, gr_w, gi_w, W16);
    // 2) qkv GEMM (M=192, K=256)
    gemm_f16<192, 256, 0><<<dim3(432), blk, 0, stream>>>(
        Aq, Xq, qr_b, qi_b, kvr_b, kvi_b, q16, k16, vt16, nullptr, nullptr, nullptr);
    // 3) fused MFMA attention -> a16 pos-major
    attn_mfma<<<dim3(36, 16, 2), blk, 0, stream>>>(q16, k16, vt16, a16);
    // 4) fused proj GEMM + LN + Xg build (one launch)
    proj_ln<<<dim3(576), blk, 0, stream>>>(a16, Ap, pr_b, pi_b,
                                           pr_lnw, pr_lnb, pi_lnw, pi_lnb,
                                           f_rgb, f_ir, Xg);
    // 5) gate GEMM (M=256, K=512) + sigmoid + residual -> out
    gemm_f16<256, 512, 2><<<dim3(576), blk, 0, stream>>>(
        Ag, Xg, gr_b, gi_b, nullptr, nullptr, nullptr, nullptr, nullptr, f_rgb, f_ir, outp);
}